// Round 1
// baseline (775.100 us; speedup 1.0000x reference)
//
#include <hip/hip_runtime.h>

// Block: LN1 -> per-head QKV -> causal attn -> proj+resid -> LN2 -> FF(relu)+resid
// B=4, T=2048, C=1024, H=16, HD=64.  All GEMMs bf16 MFMA (16x16x32), fp32 accum.

#define B_ 4
#define T_ 2048
#define C_ 1024
#define H_ 16

typedef __attribute__((ext_vector_type(8))) __bf16 bf16x8;
typedef __attribute__((ext_vector_type(4))) __bf16 bf16x4;
typedef __attribute__((ext_vector_type(4))) float f32x4;

__device__ __forceinline__ void gload_lds16(const void* g, void* l) {
  __builtin_amdgcn_global_load_lds((const __attribute__((address_space(1))) void*)g,
                                   (__attribute__((address_space(3))) void*)l, 16, 0, 0);
}

// ---------------- transpose fp32 [R][Cc] -> bf16 [Cc][R], batched ----------------
__global__ __launch_bounds__(256) void transpose_f32_bf16(
    const float* __restrict__ in, __bf16* __restrict__ out,
    int R, int Cc, long inBatch, long outBatch) {
  __shared__ float tile[32][33];
  const int tx = threadIdx.x, ty = threadIdx.y;
  in += (long)blockIdx.z * inBatch;
  out += (long)blockIdx.z * outBatch;
  const int r0 = blockIdx.y * 32, c0 = blockIdx.x * 32;
#pragma unroll
  for (int i = 0; i < 4; i++)
    tile[ty + i * 8][tx] = in[(long)(r0 + ty + i * 8) * Cc + c0 + tx];
  __syncthreads();
#pragma unroll
  for (int i = 0; i < 4; i++)
    out[(long)(c0 + ty + i * 8) * R + r0 + tx] = (__bf16)tile[tx][ty + i * 8];
}

// ---------------- LayerNorm: fp32 [rows][1024] -> bf16 ----------------
__global__ __launch_bounds__(256) void ln_fwd(const float* __restrict__ x,
                                              const float* __restrict__ g,
                                              const float* __restrict__ bta,
                                              __bf16* __restrict__ out) {
  const long row = blockIdx.x;
  const int tid = threadIdx.x;
  float4 v = ((const float4*)(x + row * C_))[tid];
  float vals[4] = {v.x, v.y, v.z, v.w};
  float s = vals[0] + vals[1] + vals[2] + vals[3];
  float s2 = vals[0] * vals[0] + vals[1] * vals[1] + vals[2] * vals[2] + vals[3] * vals[3];
#pragma unroll
  for (int o = 1; o < 64; o <<= 1) {
    s += __shfl_xor(s, o);
    s2 += __shfl_xor(s2, o);
  }
  __shared__ float red[8];
  const int lane = tid & 63, wid = tid >> 6;
  if (lane == 0) { red[wid] = s; red[wid + 4] = s2; }
  __syncthreads();
  const float S = red[0] + red[1] + red[2] + red[3];
  const float S2 = red[4] + red[5] + red[6] + red[7];
  const float mu = S * (1.0f / C_);
  const float var = S2 * (1.0f / C_) - mu * mu;
  const float rs = rsqrtf(var + 1e-5f);
  bf16x4 o4;
#pragma unroll
  for (int j = 0; j < 4; j++) {
    const int c = tid * 4 + j;
    o4[j] = (__bf16)((vals[j] - mu) * rs * g[c] + bta[c]);
  }
  *(bf16x4*)(out + row * C_ + tid * 4) = o4;
}

// ---------------- GEMM: A[M,K] bf16 x Bt[N,K] bf16 -> out [M,N] ----------------
// 128x128 tile, BK=32, 4 waves (2x2), each wave 64x64 = 4x4 frags of 16x16x32.
template <int OUT_BF16, int RELU, int HAS_BIAS, int HAS_RES>
__global__ __launch_bounds__(256, 2) void gemm_bt(
    const __bf16* __restrict__ A, const __bf16* __restrict__ Bt, void* outp,
    const float* __restrict__ bias, const float* resid, int M, int N, int K) {
  __shared__ __bf16 As[128 * 32];
  __shared__ __bf16 Bs[128 * 32];
  const int tid = threadIdx.x, lane = tid & 63, wid = tid >> 6;
  const long mBase = (long)blockIdx.y * 128, nBase = (long)blockIdx.x * 128;
  const int wm = wid >> 1, wn = wid & 1;
  const int l15 = lane & 15, kHalf = (lane >> 4) * 8;
  f32x4 acc[4][4] = {};
  const int sRow = wid * 16 + (lane >> 2);
  const int sCol = (lane & 3) * 8;
  const __bf16* aP = A + (mBase + sRow) * (long)K + sCol;
  const __bf16* bP = Bt + (nBase + sRow) * (long)K + sCol;
  const int ldsOff = sRow * 32 + sCol;  // == wid*512 + lane*8 (linear, lane0 = wave base)
  for (int kt = 0; kt < K; kt += 32) {
    gload_lds16(aP, As + ldsOff);
    gload_lds16(aP + 64 * (long)K, As + ldsOff + 2048);
    gload_lds16(bP, Bs + ldsOff);
    gload_lds16(bP + 64 * (long)K, Bs + ldsOff + 2048);
    aP += 32; bP += 32;
    __syncthreads();
    bf16x8 af[4], bfr[4];
#pragma unroll
    for (int mi = 0; mi < 4; mi++)
      af[mi] = *(const bf16x8*)&As[(wm * 64 + mi * 16 + l15) * 32 + kHalf];
#pragma unroll
    for (int ni = 0; ni < 4; ni++)
      bfr[ni] = *(const bf16x8*)&Bs[(wn * 64 + ni * 16 + l15) * 32 + kHalf];
#pragma unroll
    for (int mi = 0; mi < 4; mi++)
#pragma unroll
      for (int ni = 0; ni < 4; ni++)
        acc[mi][ni] = __builtin_amdgcn_mfma_f32_16x16x32_bf16(af[mi], bfr[ni], acc[mi][ni], 0, 0, 0);
    __syncthreads();
  }
#pragma unroll
  for (int mi = 0; mi < 4; mi++) {
#pragma unroll
    for (int ni = 0; ni < 4; ni++) {
      const long row0 = mBase + wm * 64 + mi * 16 + (lane >> 4) * 4;
      const long col = nBase + wn * 64 + ni * 16 + l15;
#pragma unroll
      for (int r = 0; r < 4; r++) {
        float vv = acc[mi][ni][r];
        if (HAS_BIAS) vv += bias[col];
        if (HAS_RES) vv += resid[(row0 + r) * N + col];
        if (RELU) vv = fmaxf(vv, 0.0f);
        if (OUT_BF16) ((__bf16*)outp)[(row0 + r) * N + col] = (__bf16)vv;
        else ((float*)outp)[(row0 + r) * N + col] = vv;
      }
    }
  }
}

// ---------------- causal flash attention ----------------
// Q,K,V layout [B,T,H*64] bf16. grid: (T/64, B*H). 4 waves, each 16 q-rows, KBLK=32.
__global__ __launch_bounds__(256, 2) void attn_fwd(
    const __bf16* __restrict__ Q, const __bf16* __restrict__ Kg,
    const __bf16* __restrict__ Vg, __bf16* __restrict__ O) {
  __shared__ __bf16 Ks[32 * 64];
  __shared__ __bf16 Vt[64 * 32];
  __shared__ __bf16 Ps[4 * 16 * 32];
  const int tid = threadIdx.x, lane = tid & 63, wid = tid >> 6;
  const int bh = blockIdx.y, b = bh >> 4, h = bh & 15;
  const int qB = blockIdx.x * 64;
  const int q0 = qB + wid * 16;
  const long bT = (long)b * T_;
  const int kGrp = (lane >> 4) * 8;
  const int l15 = lane & 15;

  bf16x8 aQ[2];
#pragma unroll
  for (int hf = 0; hf < 2; hf++)
    aQ[hf] = *(const bf16x8*)(Q + (bT + q0 + l15) * C_ + h * 64 + hf * 32 + kGrp);

  f32x4 o[4] = {};
  float m_[4] = {-1e30f, -1e30f, -1e30f, -1e30f};
  float l_[4] = {0.f, 0.f, 0.f, 0.f};

  const int nkt = blockIdx.x * 2 + 2;
  const int krow = tid >> 3, c8 = (tid & 7) * 8;
  for (int kt = 0; kt < nkt; kt++) {
    const int k0 = kt * 32;
    // stage K (direct-to-LDS, linear) and V (transposed via regs)
    gload_lds16(Kg + (bT + k0 + krow) * C_ + h * 64 + c8, &Ks[tid * 8]);
    {
      bf16x8 vv = *(const bf16x8*)(Vg + (bT + k0 + krow) * C_ + h * 64 + c8);
#pragma unroll
      for (int j = 0; j < 8; j++) Vt[(c8 + j) * 32 + krow] = vv[j];
    }
    __syncthreads();
    if (k0 <= q0 + 15) {  // tile has unmasked cols for this wave
      f32x4 s0 = {}, s1 = {};
#pragma unroll
      for (int hf = 0; hf < 2; hf++) {
        bf16x8 b0 = *(const bf16x8*)&Ks[l15 * 64 + hf * 32 + kGrp];
        bf16x8 b1 = *(const bf16x8*)&Ks[(16 + l15) * 64 + hf * 32 + kGrp];
        s0 = __builtin_amdgcn_mfma_f32_16x16x32_bf16(aQ[hf], b0, s0, 0, 0, 0);
        s1 = __builtin_amdgcn_mfma_f32_16x16x32_bf16(aQ[hf], b1, s1, 0, 0, 0);
      }
#pragma unroll
      for (int r = 0; r < 4; r++) {
        const int qrow = q0 + (lane >> 4) * 4 + r;
        float v0 = s0[r] * 0.125f;
        if (k0 + l15 > qrow) v0 = -1e30f;
        float v1 = s1[r] * 0.125f;
        if (k0 + 16 + l15 > qrow) v1 = -1e30f;
        float rmax = fmaxf(v0, v1);
#pragma unroll
        for (int off = 1; off < 16; off <<= 1) rmax = fmaxf(rmax, __shfl_xor(rmax, off));
        const float mnew = fmaxf(m_[r], rmax);
        const float fac = __expf(m_[r] - mnew);
        const float p0 = __expf(v0 - mnew), p1 = __expf(v1 - mnew);
        float rsum = p0 + p1;
#pragma unroll
        for (int off = 1; off < 16; off <<= 1) rsum += __shfl_xor(rsum, off);
        l_[r] = l_[r] * fac + rsum;
        m_[r] = mnew;
        o[0][r] *= fac; o[1][r] *= fac; o[2][r] *= fac; o[3][r] *= fac;
        const int prow = (lane >> 4) * 4 + r;
        Ps[wid * 512 + prow * 32 + l15] = (__bf16)p0;
        Ps[wid * 512 + prow * 32 + 16 + l15] = (__bf16)p1;
      }
      // PV: A = P[16x32] (per-wave LDS), B = Vt rows
      bf16x8 aPf = *(const bf16x8*)&Ps[wid * 512 + l15 * 32 + kGrp];
#pragma unroll
      for (int dg = 0; dg < 4; dg++) {
        bf16x8 bV = *(const bf16x8*)&Vt[(dg * 16 + l15) * 32 + kGrp];
        o[dg] = __builtin_amdgcn_mfma_f32_16x16x32_bf16(aPf, bV, o[dg], 0, 0, 0);
      }
    }
    __syncthreads();
  }
#pragma unroll
  for (int r = 0; r < 4; r++) {
    const float inv = 1.0f / l_[r];
    const int qrow = q0 + (lane >> 4) * 4 + r;
#pragma unroll
    for (int dg = 0; dg < 4; dg++)
      O[(bT + qrow) * C_ + h * 64 + dg * 16 + l15] = (__bf16)(o[dg][r] * inv);
  }
}

// ---------------- launch ----------------
extern "C" void kernel_launch(void* const* d_in, const int* in_sizes, int n_in,
                              void* d_out, int out_size, void* d_ws, size_t ws_size,
                              hipStream_t stream) {
  const float* x = (const float*)d_in[0];
  const float* wq = (const float*)d_in[1];
  const float* wk = (const float*)d_in[2];
  const float* wv = (const float*)d_in[3];
  const float* wproj = (const float*)d_in[4];
  const float* bproj = (const float*)d_in[5];
  const float* w1 = (const float*)d_in[6];
  const float* b1 = (const float*)d_in[7];
  const float* w2 = (const float*)d_in[8];
  const float* b2 = (const float*)d_in[9];
  const float* g1 = (const float*)d_in[10];
  const float* be1 = (const float*)d_in[11];
  const float* g2 = (const float*)d_in[12];
  const float* be2 = (const float*)d_in[13];

  char* ws = (char*)d_ws;
  const size_t MB = 1024ull * 1024ull;
  __bf16* h1 = (__bf16*)(ws + 0);          // 16MB; reused as att after QKV
  __bf16* Qb = (__bf16*)(ws + 16 * MB);    // 16MB; reused as h2 after attn
  __bf16* Kb = (__bf16*)(ws + 32 * MB);    // 16MB
  __bf16* Vb = (__bf16*)(ws + 48 * MB);    // 16MB
  __bf16* ff1 = (__bf16*)(ws + 32 * MB);   // 64MB, aliases Kb/Vb (dead after attn)
  __bf16* wqt = (__bf16*)(ws + 96 * MB);   // 2MB each
  __bf16* wkt = (__bf16*)(ws + 98 * MB);
  __bf16* wvt = (__bf16*)(ws + 100 * MB);
  __bf16* wpt = (__bf16*)(ws + 102 * MB);
  __bf16* w1t = (__bf16*)(ws + 104 * MB);  // 8MB
  __bf16* w2t = (__bf16*)(ws + 112 * MB);  // 8MB
  __bf16* att = h1;
  __bf16* h2 = Qb;
  float* xout = (float*)d_out;

  dim3 tb(32, 8);
  // weight transposes (fp32 -> bf16, [K][N] -> [N][K]); qkv per-head
  transpose_f32_bf16<<<dim3(2, 32, 16), tb, 0, stream>>>(wq, wqt, 1024, 64, 1024 * 64, 64 * 1024);
  transpose_f32_bf16<<<dim3(2, 32, 16), tb, 0, stream>>>(wk, wkt, 1024, 64, 1024 * 64, 64 * 1024);
  transpose_f32_bf16<<<dim3(2, 32, 16), tb, 0, stream>>>(wv, wvt, 1024, 64, 1024 * 64, 64 * 1024);
  transpose_f32_bf16<<<dim3(32, 32, 1), tb, 0, stream>>>(wproj, wpt, 1024, 1024, 0, 0);
  transpose_f32_bf16<<<dim3(128, 32, 1), tb, 0, stream>>>(w1, w1t, 1024, 4096, 0, 0);
  transpose_f32_bf16<<<dim3(32, 128, 1), tb, 0, stream>>>(w2, w2t, 4096, 1024, 0, 0);

  ln_fwd<<<8192, 256, 0, stream>>>(x, g1, be1, h1);
  gemm_bt<1, 0, 0, 0><<<dim3(8, 64), 256, 0, stream>>>(h1, wqt, Qb, nullptr, nullptr, 8192, 1024, 1024);
  gemm_bt<1, 0, 0, 0><<<dim3(8, 64), 256, 0, stream>>>(h1, wkt, Kb, nullptr, nullptr, 8192, 1024, 1024);
  gemm_bt<1, 0, 0, 0><<<dim3(8, 64), 256, 0, stream>>>(h1, wvt, Vb, nullptr, nullptr, 8192, 1024, 1024);
  attn_fwd<<<dim3(32, 64), 256, 0, stream>>>(Qb, Kb, Vb, att);
  gemm_bt<0, 0, 1, 1><<<dim3(8, 64), 256, 0, stream>>>(att, wpt, xout, bproj, x, 8192, 1024, 1024);
  ln_fwd<<<8192, 256, 0, stream>>>(xout, g2, be2, h2);
  gemm_bt<1, 1, 1, 0><<<dim3(32, 64), 256, 0, stream>>>(h2, w1t, ff1, b1, nullptr, 8192, 4096, 1024);
  gemm_bt<0, 0, 1, 1><<<dim3(8, 64), 256, 0, stream>>>(ff1, w2t, xout, b2, (const float*)xout, 8192, 1024, 4096);
}

// Round 2
// 475.396 us; speedup vs baseline: 1.6304x; 1.6304x over previous
//
#include <hip/hip_runtime.h>

// Block: LN1 -> per-head QKV -> causal attn -> proj+resid -> LN2 -> FF(relu)+resid
// B=4, T=2048, C=1024, H=16, HD=64.  All GEMMs bf16 MFMA (16x16x32), fp32 accum.

#define B_ 4
#define T_ 2048
#define C_ 1024
#define H_ 16
#define BT_ 8192

typedef __attribute__((ext_vector_type(8))) __bf16 bf16x8;
typedef __attribute__((ext_vector_type(4))) __bf16 bf16x4;
typedef __attribute__((ext_vector_type(4))) float f32x4;

__device__ __forceinline__ void gload_lds16(const void* g, void* l) {
  __builtin_amdgcn_global_load_lds((const __attribute__((address_space(1))) void*)g,
                                   (__attribute__((address_space(3))) void*)l, 16, 0, 0);
}

// ---------------- transpose fp32 [R][Cc] -> bf16 [Cc][R], batched ----------------
__global__ __launch_bounds__(256) void transpose_f32_bf16(
    const float* __restrict__ in, __bf16* __restrict__ out,
    int R, int Cc, long inBatch, long outBatch) {
  __shared__ float tile[32][33];
  const int tx = threadIdx.x, ty = threadIdx.y;
  in += (long)blockIdx.z * inBatch;
  out += (long)blockIdx.z * outBatch;
  const int r0 = blockIdx.y * 32, c0 = blockIdx.x * 32;
#pragma unroll
  for (int i = 0; i < 4; i++)
    tile[ty + i * 8][tx] = in[(long)(r0 + ty + i * 8) * Cc + c0 + tx];
  __syncthreads();
#pragma unroll
  for (int i = 0; i < 4; i++)
    out[(long)(c0 + ty + i * 8) * R + r0 + tx] = (__bf16)tile[tx][ty + i * 8];
}

// ---------------- LayerNorm: fp32 [rows][1024] -> bf16 ----------------
__global__ __launch_bounds__(256) void ln_fwd(const float* __restrict__ x,
                                              const float* __restrict__ g,
                                              const float* __restrict__ bta,
                                              __bf16* __restrict__ out) {
  const long row = blockIdx.x;
  const int tid = threadIdx.x;
  float4 v = ((const float4*)(x + row * C_))[tid];
  float vals[4] = {v.x, v.y, v.z, v.w};
  float s = vals[0] + vals[1] + vals[2] + vals[3];
  float s2 = vals[0] * vals[0] + vals[1] * vals[1] + vals[2] * vals[2] + vals[3] * vals[3];
#pragma unroll
  for (int o = 1; o < 64; o <<= 1) {
    s += __shfl_xor(s, o);
    s2 += __shfl_xor(s2, o);
  }
  __shared__ float red[8];
  const int lane = tid & 63, wid = tid >> 6;
  if (lane == 0) { red[wid] = s; red[wid + 4] = s2; }
  __syncthreads();
  const float S = red[0] + red[1] + red[2] + red[3];
  const float S2 = red[4] + red[5] + red[6] + red[7];
  const float mu = S * (1.0f / C_);
  const float var = S2 * (1.0f / C_) - mu * mu;
  const float rs = rsqrtf(var + 1e-5f);
  bf16x4 o4;
#pragma unroll
  for (int j = 0; j < 4; j++) {
    const int c = tid * 4 + j;
    o4[j] = (__bf16)((vals[j] - mu) * rs * g[c] + bta[c]);
  }
  *(bf16x4*)(out + row * C_ + tid * 4) = o4;
}

// ---------------- GEMM: A[M,K] bf16 x Bt[N,K] bf16 -> out [M,N] ----------------
// 128x128 tile, BK=32, 4 waves (2x2), each wave 64x64 = 4x4 frags of 16x16x32.
// TRANSO: write output transposed as out[col][row] with leading dim M (for V).
template <int OUT_BF16, int RELU, int HAS_BIAS, int HAS_RES, int TRANSO>
__global__ __launch_bounds__(256, 2) void gemm_bt(
    const __bf16* __restrict__ A, const __bf16* __restrict__ Bt, void* outp,
    const float* __restrict__ bias, const float* resid, int M, int N, int K) {
  __shared__ __bf16 As[128 * 32];
  __shared__ __bf16 Bs[128 * 32];
  const int tid = threadIdx.x, lane = tid & 63, wid = tid >> 6;
  const long mBase = (long)blockIdx.y * 128, nBase = (long)blockIdx.x * 128;
  const int wm = wid >> 1, wn = wid & 1;
  const int l15 = lane & 15, kHalf = (lane >> 4) * 8;
  f32x4 acc[4][4] = {};
  const int sRow = wid * 16 + (lane >> 2);
  const int sCol = (lane & 3) * 8;
  const __bf16* aP = A + (mBase + sRow) * (long)K + sCol;
  const __bf16* bP = Bt + (nBase + sRow) * (long)K + sCol;
  const int ldsOff = sRow * 32 + sCol;
  for (int kt = 0; kt < K; kt += 32) {
    gload_lds16(aP, As + ldsOff);
    gload_lds16(aP + 64 * (long)K, As + ldsOff + 2048);
    gload_lds16(bP, Bs + ldsOff);
    gload_lds16(bP + 64 * (long)K, Bs + ldsOff + 2048);
    aP += 32; bP += 32;
    __syncthreads();
    bf16x8 af[4], bfr[4];
#pragma unroll
    for (int mi = 0; mi < 4; mi++)
      af[mi] = *(const bf16x8*)&As[(wm * 64 + mi * 16 + l15) * 32 + kHalf];
#pragma unroll
    for (int ni = 0; ni < 4; ni++)
      bfr[ni] = *(const bf16x8*)&Bs[(wn * 64 + ni * 16 + l15) * 32 + kHalf];
#pragma unroll
    for (int mi = 0; mi < 4; mi++)
#pragma unroll
      for (int ni = 0; ni < 4; ni++)
        acc[mi][ni] = __builtin_amdgcn_mfma_f32_16x16x32_bf16(af[mi], bfr[ni], acc[mi][ni], 0, 0, 0);
    __syncthreads();
  }
#pragma unroll
  for (int mi = 0; mi < 4; mi++) {
#pragma unroll
    for (int ni = 0; ni < 4; ni++) {
      const long row0 = mBase + wm * 64 + mi * 16 + (lane >> 4) * 4;
      const long col = nBase + wn * 64 + ni * 16 + l15;
#pragma unroll
      for (int r = 0; r < 4; r++) {
        float vv = acc[mi][ni][r];
        if (HAS_BIAS) vv += bias[col];
        if (HAS_RES) vv += resid[(row0 + r) * N + col];
        if (RELU) vv = fmaxf(vv, 0.0f);
        if (OUT_BF16) {
          if (TRANSO) ((__bf16*)outp)[col * (long)M + row0 + r] = (__bf16)vv;
          else ((__bf16*)outp)[(row0 + r) * N + col] = (__bf16)vv;
        } else {
          ((float*)outp)[(row0 + r) * N + col] = vv;
        }
      }
    }
  }
}

// ---------------- causal flash attention v2 ----------------
// Q [B,T,C] bf16;  K [B,T,C] bf16;  Vt [C][B*T] bf16 (pre-transposed by V-GEMM).
// grid (16, B*H); 512 threads = 8 waves x 16 q-rows; KBLK=64, double-buffered.
// Swapped QK^T: S^T = mfma(A=K, B=Q) -> lane holds S^T[.][q=l15]; in-reg softmax.
#define PSTR 72
__global__ __launch_bounds__(512, 6) void attn_fwd2(
    const __bf16* __restrict__ Qg, const __bf16* __restrict__ Kg,
    const __bf16* __restrict__ Vtg, __bf16* __restrict__ O) {
  __shared__ __bf16 Ks[2][64 * 64];
  __shared__ __bf16 Vs[2][64 * 64];
  __shared__ __bf16 Ps[128 * PSTR];
  const int tid = threadIdx.x, lane = tid & 63, wid = tid >> 6;
  const int bh = blockIdx.y, b = bh >> 4, h = bh & 15;
  const int qx = 15 - blockIdx.x;           // heavy blocks first
  const int qBase = qx * 128;
  const int qw = qBase + wid * 16;          // this wave's q block
  const int qwTop = qw + 15;
  const long bT = (long)b * T_;
  const int l15 = lane & 15, qtr = lane >> 4;
  const int q_lane = qw + l15;              // softmax row owned by this lane

  // staging geometry: thread stages chunk p of each 64x64 tile (16B chunks)
  const int srow = tid >> 3;
  const int schunk = (tid & 7) ^ (srow & 7);  // pre-swizzled source chunk
  const __bf16* kSrcBase = Kg + (bT + srow) * C_ + h * 64 + schunk * 8;
  const __bf16* vSrcBase = Vtg + (long)(h * 64 + srow) * BT_ + bT + schunk * 8;
  __bf16* kDst = &Ks[0][tid * 8];
  __bf16* vDst = &Vs[0][tid * 8];
  const int bufStride = 64 * 64;

  // Q fragments (B-operand), pre-scaled by 1/sqrt(64)=0.125
  bf16x8 q0s, q1s;
  {
    bf16x8 r0 = *(const bf16x8*)(Qg + (bT + q_lane) * C_ + h * 64 + qtr * 8);
    bf16x8 r1 = *(const bf16x8*)(Qg + (bT + q_lane) * C_ + h * 64 + 32 + qtr * 8);
#pragma unroll
    for (int j = 0; j < 8; j++) {
      q0s[j] = (__bf16)((float)r0[j] * 0.125f);
      q1s[j] = (__bf16)((float)r1[j] * 0.125f);
    }
  }

  f32x4 o[4] = {};
  float m_ = -1e30f, l_ = 0.0f;
  const int nkt = 2 * qx + 2;

  // prologue: stage tile 0 into buf 0
  gload_lds16(kSrcBase, kDst);
  gload_lds16(vSrcBase, vDst);
  __syncthreads();

  int buf = 0;
  for (int t = 0; t < nkt; t++) {
    const int k0 = t * 64;
    if (t + 1 < nkt) {  // stage next tile into buf^1 (overlapped with compute)
      const long koff = (long)(k0 + 64);
      gload_lds16(kSrcBase + koff * C_, kDst + (buf ^ 1) * bufStride);
      gload_lds16(vSrcBase + koff, vDst + (buf ^ 1) * bufStride);
    }
    if (k0 <= qwTop) {
      const __bf16* ks = Ks[buf];
      const __bf16* vs = Vs[buf];
      // ---- QK^T (swapped): sT[kb] = S^T[kb*16 .. +16)[q=l15]
      f32x4 sT[4] = {};
      __builtin_amdgcn_s_setprio(1);
#pragma unroll
      for (int kb = 0; kb < 4; kb++) {
        bf16x8 aK0 = *(const bf16x8*)&ks[(kb * 16 + l15) * 64 + ((qtr ^ (l15 & 7)) * 8)];
        bf16x8 aK1 = *(const bf16x8*)&ks[(kb * 16 + l15) * 64 + (((4 + qtr) ^ (l15 & 7)) * 8)];
        sT[kb] = __builtin_amdgcn_mfma_f32_16x16x32_bf16(aK0, q0s, sT[kb], 0, 0, 0);
        sT[kb] = __builtin_amdgcn_mfma_f32_16x16x32_bf16(aK1, q1s, sT[kb], 0, 0, 0);
      }
      __builtin_amdgcn_s_setprio(0);
      // ---- causal mask (only near diagonal)
      if (k0 + 63 > qw) {
#pragma unroll
        for (int kb = 0; kb < 4; kb++)
#pragma unroll
          for (int r = 0; r < 4; r++)
            if (k0 + kb * 16 + qtr * 4 + r > q_lane) sT[kb][r] = -1e30f;
      }
      // ---- online softmax (per-lane row q=l15; cross-quarter via 2 shfl)
      float mx = -1e30f;
#pragma unroll
      for (int kb = 0; kb < 4; kb++)
#pragma unroll
        for (int r = 0; r < 4; r++) mx = fmaxf(mx, sT[kb][r]);
      mx = fmaxf(mx, __shfl_xor(mx, 16));
      mx = fmaxf(mx, __shfl_xor(mx, 32));
      const float mnew = fmaxf(m_, mx);
      const float fac = __expf(m_ - mnew);
      float psum = 0.0f;
#pragma unroll
      for (int kb = 0; kb < 4; kb++)
#pragma unroll
        for (int r = 0; r < 4; r++) {
          const float pv = __expf(sT[kb][r] - mnew);
          psum += pv;
          Ps[(wid * 16 + l15) * PSTR + kb * 16 + qtr * 4 + r] = (__bf16)pv;
        }
      psum += __shfl_xor(psum, 16);
      psum += __shfl_xor(psum, 32);
      l_ = l_ * fac + psum;
      m_ = mnew;
      // ---- rescale O (gather per-output-row factor)
#pragma unroll
      for (int r = 0; r < 4; r++) {
        const float fr = __shfl(fac, (lane & 48) + qtr * 4 + r);
#pragma unroll
        for (int dg = 0; dg < 4; dg++) o[dg][r] *= fr;
      }
      // ---- PV: O[q][d] += P[q][k] * V[k][d]
      __builtin_amdgcn_s_setprio(1);
#pragma unroll
      for (int s = 0; s < 2; s++) {
        bf16x8 aP = *(const bf16x8*)&Ps[(wid * 16 + l15) * PSTR + s * 32 + qtr * 8];
#pragma unroll
        for (int dg = 0; dg < 4; dg++) {
          bf16x8 bV = *(const bf16x8*)&vs[(dg * 16 + l15) * 64 + (((s * 4 + qtr) ^ (l15 & 7)) * 8)];
          o[dg] = __builtin_amdgcn_mfma_f32_16x16x32_bf16(aP, bV, o[dg], 0, 0, 0);
        }
      }
      __builtin_amdgcn_s_setprio(0);
    }
    __syncthreads();  // drains staging vmcnt + publishes buf^1
    buf ^= 1;
  }

  // ---- epilogue: normalize and store
  const float linv = 1.0f / l_;
#pragma unroll
  for (int r = 0; r < 4; r++) {
    const float lr = __shfl(linv, (lane & 48) + qtr * 4 + r);
    const long row = bT + qw + qtr * 4 + r;
#pragma unroll
    for (int dg = 0; dg < 4; dg++)
      O[row * C_ + h * 64 + dg * 16 + l15] = (__bf16)(o[dg][r] * lr);
  }
}

// ---------------- launch ----------------
extern "C" void kernel_launch(void* const* d_in, const int* in_sizes, int n_in,
                              void* d_out, int out_size, void* d_ws, size_t ws_size,
                              hipStream_t stream) {
  const float* x = (const float*)d_in[0];
  const float* wq = (const float*)d_in[1];
  const float* wk = (const float*)d_in[2];
  const float* wv = (const float*)d_in[3];
  const float* wproj = (const float*)d_in[4];
  const float* bproj = (const float*)d_in[5];
  const float* w1 = (const float*)d_in[6];
  const float* b1 = (const float*)d_in[7];
  const float* w2 = (const float*)d_in[8];
  const float* b2 = (const float*)d_in[9];
  const float* g1 = (const float*)d_in[10];
  const float* be1 = (const float*)d_in[11];
  const float* g2 = (const float*)d_in[12];
  const float* be2 = (const float*)d_in[13];

  char* ws = (char*)d_ws;
  const size_t MB = 1024ull * 1024ull;
  __bf16* h1 = (__bf16*)(ws + 0);          // 16MB; reused as att after QKV
  __bf16* Qb = (__bf16*)(ws + 16 * MB);    // 16MB; reused as h2 after attn
  __bf16* Kb = (__bf16*)(ws + 32 * MB);    // 16MB
  __bf16* Vtg = (__bf16*)(ws + 48 * MB);   // 16MB, V pre-transposed [C][B*T]
  __bf16* ff1 = (__bf16*)(ws + 32 * MB);   // 64MB, aliases Kb/Vtg (dead after attn)
  __bf16* wqt = (__bf16*)(ws + 96 * MB);   // 2MB each
  __bf16* wkt = (__bf16*)(ws + 98 * MB);
  __bf16* wvt = (__bf16*)(ws + 100 * MB);
  __bf16* wpt = (__bf16*)(ws + 102 * MB);
  __bf16* w1t = (__bf16*)(ws + 104 * MB);  // 8MB
  __bf16* w2t = (__bf16*)(ws + 112 * MB);  // 8MB
  __bf16* att = h1;
  __bf16* h2 = Qb;
  float* xout = (float*)d_out;

  dim3 tb(32, 8);
  transpose_f32_bf16<<<dim3(2, 32, 16), tb, 0, stream>>>(wq, wqt, 1024, 64, 1024 * 64, 64 * 1024);
  transpose_f32_bf16<<<dim3(2, 32, 16), tb, 0, stream>>>(wk, wkt, 1024, 64, 1024 * 64, 64 * 1024);
  transpose_f32_bf16<<<dim3(2, 32, 16), tb, 0, stream>>>(wv, wvt, 1024, 64, 1024 * 64, 64 * 1024);
  transpose_f32_bf16<<<dim3(32, 32, 1), tb, 0, stream>>>(wproj, wpt, 1024, 1024, 0, 0);
  transpose_f32_bf16<<<dim3(128, 32, 1), tb, 0, stream>>>(w1, w1t, 1024, 4096, 0, 0);
  transpose_f32_bf16<<<dim3(32, 128, 1), tb, 0, stream>>>(w2, w2t, 4096, 1024, 0, 0);

  ln_fwd<<<8192, 256, 0, stream>>>(x, g1, be1, h1);
  gemm_bt<1, 0, 0, 0, 0><<<dim3(8, 64), 256, 0, stream>>>(h1, wqt, Qb, nullptr, nullptr, 8192, 1024, 1024);
  gemm_bt<1, 0, 0, 0, 0><<<dim3(8, 64), 256, 0, stream>>>(h1, wkt, Kb, nullptr, nullptr, 8192, 1024, 1024);
  gemm_bt<1, 0, 0, 0, 1><<<dim3(8, 64), 256, 0, stream>>>(h1, wvt, Vtg, nullptr, nullptr, 8192, 1024, 1024);
  attn_fwd2<<<dim3(16, 64), 512, 0, stream>>>(Qb, Kb, Vtg, att);
  gemm_bt<0, 0, 1, 1, 0><<<dim3(8, 64), 256, 0, stream>>>(att, wpt, xout, bproj, x, 8192, 1024, 1024);
  ln_fwd<<<8192, 256, 0, stream>>>(xout, g2, be2, h2);
  gemm_bt<1, 1, 1, 0, 0><<<dim3(32, 64), 256, 0, stream>>>(h2, w1t, ff1, b1, nullptr, 8192, 4096, 1024);
  gemm_bt<0, 0, 1, 1, 0><<<dim3(8, 64), 256, 0, stream>>>(ff1, w2t, xout, b2, (const float*)xout, 8192, 1024, 4096);
}

// Round 3
// 467.366 us; speedup vs baseline: 1.6584x; 1.0172x over previous
//
#include <hip/hip_runtime.h>

// Block: LN1 -> per-head QKV -> causal attn -> proj+resid -> LN2 -> FF(relu)+resid
// B=4, T=2048, C=1024, H=16, HD=64.  All GEMMs bf16 MFMA (16x16x32), fp32 accum.

#define B_ 4
#define T_ 2048
#define C_ 1024
#define H_ 16
#define BT_ 8192

typedef __attribute__((ext_vector_type(8))) __bf16 bf16x8;
typedef __attribute__((ext_vector_type(4))) __bf16 bf16x4;
typedef __attribute__((ext_vector_type(4))) float f32x4;

#define WAIT_LGKM0 asm volatile("s_waitcnt lgkmcnt(0)" ::: "memory")
#define WAIT_VM4 asm volatile("s_waitcnt vmcnt(4)" ::: "memory")
#define WAIT_VM0 asm volatile("s_waitcnt vmcnt(0)" ::: "memory")

__device__ __forceinline__ void gload_lds16(const void* g, void* l) {
  __builtin_amdgcn_global_load_lds((const __attribute__((address_space(1))) void*)g,
                                   (__attribute__((address_space(3))) void*)l, 16, 0, 0);
}

__device__ __forceinline__ void block_sync() {
  asm volatile("" ::: "memory");
  __builtin_amdgcn_s_barrier();
  asm volatile("" ::: "memory");
}

// ---------------- transpose fp32 [R][Cc] -> bf16 [Cc][R], batched ----------------
__global__ __launch_bounds__(256) void transpose_f32_bf16(
    const float* __restrict__ in, __bf16* __restrict__ out,
    int R, int Cc, long inBatch, long outBatch) {
  __shared__ float tile[32][33];
  const int tx = threadIdx.x, ty = threadIdx.y;
  in += (long)blockIdx.z * inBatch;
  out += (long)blockIdx.z * outBatch;
  const int r0 = blockIdx.y * 32, c0 = blockIdx.x * 32;
#pragma unroll
  for (int i = 0; i < 4; i++)
    tile[ty + i * 8][tx] = in[(long)(r0 + ty + i * 8) * Cc + c0 + tx];
  __syncthreads();
#pragma unroll
  for (int i = 0; i < 4; i++)
    out[(long)(c0 + ty + i * 8) * R + r0 + tx] = (__bf16)tile[tx][ty + i * 8];
}

// ---------------- LayerNorm: fp32 [rows][1024] -> bf16 ----------------
__global__ __launch_bounds__(256) void ln_fwd(const float* __restrict__ x,
                                              const float* __restrict__ g,
                                              const float* __restrict__ bta,
                                              __bf16* __restrict__ out) {
  const long row = blockIdx.x;
  const int tid = threadIdx.x;
  float4 v = ((const float4*)(x + row * C_))[tid];
  float vals[4] = {v.x, v.y, v.z, v.w};
  float s = vals[0] + vals[1] + vals[2] + vals[3];
  float s2 = vals[0] * vals[0] + vals[1] * vals[1] + vals[2] * vals[2] + vals[3] * vals[3];
#pragma unroll
  for (int o = 1; o < 64; o <<= 1) {
    s += __shfl_xor(s, o);
    s2 += __shfl_xor(s2, o);
  }
  __shared__ float red[8];
  const int lane = tid & 63, wid = tid >> 6;
  if (lane == 0) { red[wid] = s; red[wid + 4] = s2; }
  __syncthreads();
  const float S = red[0] + red[1] + red[2] + red[3];
  const float S2 = red[4] + red[5] + red[6] + red[7];
  const float mu = S * (1.0f / C_);
  const float var = S2 * (1.0f / C_) - mu * mu;
  const float rs = rsqrtf(var + 1e-5f);
  bf16x4 o4;
#pragma unroll
  for (int j = 0; j < 4; j++) {
    const int c = tid * 4 + j;
    o4[j] = (__bf16)((vals[j] - mu) * rs * g[c] + bta[c]);
  }
  *(bf16x4*)(out + row * C_ + tid * 4) = o4;
}

// ---------------- GEMM (small-N): 128x128 tile, BK=32, 4 waves ----------------
template <int OUT_BF16, int RELU, int HAS_BIAS, int HAS_RES, int TRANSO>
__global__ __launch_bounds__(256, 2) void gemm_bt(
    const __bf16* __restrict__ A, const __bf16* __restrict__ Bt, void* outp,
    const float* __restrict__ bias, const float* resid, int M, int N, int K) {
  __shared__ __bf16 As[128 * 32];
  __shared__ __bf16 Bs[128 * 32];
  const int tid = threadIdx.x, lane = tid & 63, wid = tid >> 6;
  const long mBase = (long)blockIdx.y * 128, nBase = (long)blockIdx.x * 128;
  const int wm = wid >> 1, wn = wid & 1;
  const int l15 = lane & 15, kHalf = (lane >> 4) * 8;
  f32x4 acc[4][4] = {};
  const int sRow = wid * 16 + (lane >> 2);
  const int sCol = (lane & 3) * 8;
  const __bf16* aP = A + (mBase + sRow) * (long)K + sCol;
  const __bf16* bP = Bt + (nBase + sRow) * (long)K + sCol;
  const int ldsOff = sRow * 32 + sCol;
  for (int kt = 0; kt < K; kt += 32) {
    gload_lds16(aP, As + ldsOff);
    gload_lds16(aP + 64 * (long)K, As + ldsOff + 2048);
    gload_lds16(bP, Bs + ldsOff);
    gload_lds16(bP + 64 * (long)K, Bs + ldsOff + 2048);
    aP += 32; bP += 32;
    __syncthreads();
    bf16x8 af[4], bfr[4];
#pragma unroll
    for (int mi = 0; mi < 4; mi++)
      af[mi] = *(const bf16x8*)&As[(wm * 64 + mi * 16 + l15) * 32 + kHalf];
#pragma unroll
    for (int ni = 0; ni < 4; ni++)
      bfr[ni] = *(const bf16x8*)&Bs[(wn * 64 + ni * 16 + l15) * 32 + kHalf];
#pragma unroll
    for (int mi = 0; mi < 4; mi++)
#pragma unroll
      for (int ni = 0; ni < 4; ni++)
        acc[mi][ni] = __builtin_amdgcn_mfma_f32_16x16x32_bf16(af[mi], bfr[ni], acc[mi][ni], 0, 0, 0);
    __syncthreads();
  }
#pragma unroll
  for (int mi = 0; mi < 4; mi++) {
#pragma unroll
    for (int ni = 0; ni < 4; ni++) {
      const long row0 = mBase + wm * 64 + mi * 16 + (lane >> 4) * 4;
      const long col = nBase + wn * 64 + ni * 16 + l15;
#pragma unroll
      for (int r = 0; r < 4; r++) {
        float vv = acc[mi][ni][r];
        if (HAS_BIAS) vv += bias[col];
        if (HAS_RES) vv += resid[(row0 + r) * N + col];
        if (RELU) vv = fmaxf(vv, 0.0f);
        if (OUT_BF16) {
          if (TRANSO) ((__bf16*)outp)[col * (long)M + row0 + r] = (__bf16)vv;
          else ((__bf16*)outp)[(row0 + r) * N + col] = (__bf16)vv;
        } else {
          ((float*)outp)[(row0 + r) * N + col] = vv;
        }
      }
    }
  }
}

// ---------------- GEMM 256x256, 8-phase-style, 3-slot ring, counted vmcnt ----------------
// A[M,K] x Bt[N,K]. 512 thr = 8 waves (2M x 4N), per-wave 128x64 out.
// BK=32; per K-tile: 2 phases x 16 MFMA. LDS 3 slots x (A 16KB + B 16KB) = 96KB.
// Swizzle: 16B-chunk pos = chunk ^ ((row>>1)&3); staged via pre-swizzled global src.
// EPI 0: bf16 out [M,N], bias+relu (FF1).  EPI 1: QKV routing (N=3072).
template <int EPI>
__global__ __launch_bounds__(512, 2) void gemm256(
    const __bf16* __restrict__ A, const __bf16* __restrict__ Bt,
    void* out0, void* out1, void* out2,
    const float* __restrict__ bias, int M, int N, int K) {
  __shared__ __bf16 sm[3 * 16384];
  const int tid = threadIdx.x, lane = tid & 63, wid = tid >> 6;
  const int wm = wid >> 2, wn = wid & 3;
  const int l15 = lane & 15, qtr = lane >> 4;
  const long mBase = (long)blockIdx.y * 256, nBase = (long)blockIdx.x * 256;
  const int NT = K >> 5;

  f32x4 acc[8][4] = {};

  // fragment-read offsets (elements), swizzled chunk position
  const int posOff = (qtr ^ ((l15 >> 1) & 3)) * 8;
  const int aBase = (wm * 128 + l15) * 32 + posOff;
  const int bBase = (wn * 64 + l15) * 32 + posOff;

  // staging source (pre-swizzled global chunk)
  const int trow = tid >> 2;
  const long coff = (long)(((tid & 3) ^ ((tid >> 3) & 3)) * 8);
  const __bf16* aS0 = A + (mBase + trow) * (long)K + coff;
  const __bf16* aS1 = aS0 + 128 * (long)K;
  const __bf16* bS0 = Bt + (nBase + trow) * (long)K + coff;
  const __bf16* bS1 = bS0 + 128 * (long)K;

  // prologue: stage tiles 0,1 into slots 0,1
  {
    __bf16* d0 = &sm[0];
    gload_lds16(aS0, d0 + tid * 8);
    gload_lds16(aS1, d0 + 4096 + tid * 8);
    gload_lds16(bS0, d0 + 8192 + tid * 8);
    gload_lds16(bS1, d0 + 12288 + tid * 8);
    __bf16* d1 = &sm[16384];
    gload_lds16(aS0 + 32, d1 + tid * 8);
    gload_lds16(aS1 + 32, d1 + 4096 + tid * 8);
    gload_lds16(bS0 + 32, d1 + 8192 + tid * 8);
    gload_lds16(bS1 + 32, d1 + 12288 + tid * 8);
  }
  WAIT_VM4;
  block_sync();

  int sl = 0;
  for (int t = 0; t < NT; ++t) {
    const __bf16* sA = &sm[sl * 16384];
    const __bf16* sB = sA + 8192;
    const int slN = (sl + 2 >= 3) ? sl - 1 : sl + 2;
    __bf16* stA = &sm[slN * 16384];
    __bf16* stB = stA + 8192;
    const long kc = (long)(t + 2) * 32;
    const bool doStage = (t + 2 < NT);

    bf16x8 bfr[4], af[4];
    // ---- phase 0: B frags + A rows 0-63 of half; MFMA rf0-3
#pragma unroll
    for (int cf = 0; cf < 4; cf++) bfr[cf] = *(const bf16x8*)&sB[bBase + cf * 512];
#pragma unroll
    for (int rf = 0; rf < 4; rf++) af[rf] = *(const bf16x8*)&sA[aBase + rf * 512];
    if (doStage) {
      gload_lds16(aS0 + kc, stA + tid * 8);
      gload_lds16(aS1 + kc, stA + 4096 + tid * 8);
    }
    block_sync();
    WAIT_LGKM0;
    __builtin_amdgcn_s_setprio(1);
#pragma unroll
    for (int rf = 0; rf < 4; rf++)
#pragma unroll
      for (int cf = 0; cf < 4; cf++)
        acc[rf][cf] = __builtin_amdgcn_mfma_f32_16x16x32_bf16(af[rf], bfr[cf], acc[rf][cf], 0, 0, 0);
    __builtin_amdgcn_s_setprio(0);
    block_sync();

    // ---- phase 1: A rows 64-127 of half; MFMA rf4-7
#pragma unroll
    for (int rf = 0; rf < 4; rf++) af[rf] = *(const bf16x8*)&sA[aBase + 2048 + rf * 512];
    if (doStage) {
      gload_lds16(bS0 + kc, stB + tid * 8);
      gload_lds16(bS1 + kc, stB + 4096 + tid * 8);
      WAIT_VM4;
    } else {
      WAIT_VM0;
    }
    block_sync();
    WAIT_LGKM0;
    __builtin_amdgcn_s_setprio(1);
#pragma unroll
    for (int rf = 0; rf < 4; rf++)
#pragma unroll
      for (int cf = 0; cf < 4; cf++)
        acc[4 + rf][cf] = __builtin_amdgcn_mfma_f32_16x16x32_bf16(af[rf], bfr[cf], acc[4 + rf][cf], 0, 0, 0);
    __builtin_amdgcn_s_setprio(0);
    block_sync();

    sl = (sl + 1 == 3) ? 0 : sl + 1;
  }

  // ---- epilogue
  if (EPI == 0) {
    __bf16* outB = (__bf16*)out0;
#pragma unroll
    for (int cf = 0; cf < 4; cf++) {
      const long gc = nBase + wn * 64 + cf * 16 + l15;
      const float bv = bias[gc];
#pragma unroll
      for (int rfi = 0; rfi < 8; rfi++) {
        const long gr0 = mBase + wm * 128 + rfi * 16 + qtr * 4;
#pragma unroll
        for (int r = 0; r < 4; r++)
          outB[(gr0 + r) * (long)N + gc] = (__bf16)fmaxf(acc[rfi][cf][r] + bv, 0.0f);
      }
    }
  } else {
    // QKV routing: seg 0 -> Q [BT,1024], 1 -> K [BT,1024], 2 -> V transposed [1024][BT]
    const int seg = (int)(nBase >> 10);
#pragma unroll
    for (int cf = 0; cf < 4; cf++) {
      const long gc = nBase + wn * 64 + cf * 16 + l15;
      const long cc = gc & 1023;
#pragma unroll
      for (int rfi = 0; rfi < 8; rfi++) {
        const long gr0 = mBase + wm * 128 + rfi * 16 + qtr * 4;
        if (seg == 0) {
          __bf16* Qb = (__bf16*)out0;
#pragma unroll
          for (int r = 0; r < 4; r++) Qb[(gr0 + r) * 1024 + cc] = (__bf16)acc[rfi][cf][r];
        } else if (seg == 1) {
          __bf16* Kb = (__bf16*)out1;
#pragma unroll
          for (int r = 0; r < 4; r++) Kb[(gr0 + r) * 1024 + cc] = (__bf16)acc[rfi][cf][r];
        } else {
          __bf16* Vtg = (__bf16*)out2;
          bf16x4 v4;
#pragma unroll
          for (int r = 0; r < 4; r++) v4[r] = (__bf16)acc[rfi][cf][r];
          *(bf16x4*)&Vtg[cc * (long)BT_ + gr0] = v4;
        }
      }
    }
  }
}

// ---------------- causal flash attention v2 ----------------
#define PSTR 72
__global__ __launch_bounds__(512, 6) void attn_fwd2(
    const __bf16* __restrict__ Qg, const __bf16* __restrict__ Kg,
    const __bf16* __restrict__ Vtg, __bf16* __restrict__ O) {
  __shared__ __bf16 Ks[2][64 * 64];
  __shared__ __bf16 Vs[2][64 * 64];
  __shared__ __bf16 Ps[128 * PSTR];
  const int tid = threadIdx.x, lane = tid & 63, wid = tid >> 6;
  const int bh = blockIdx.y, b = bh >> 4, h = bh & 15;
  const int qx = 15 - blockIdx.x;           // heavy blocks first
  const int qBase = qx * 128;
  const int qw = qBase + wid * 16;
  const int qwTop = qw + 15;
  const long bT = (long)b * T_;
  const int l15 = lane & 15, qtr = lane >> 4;
  const int q_lane = qw + l15;

  const int srow = tid >> 3;
  const int schunk = (tid & 7) ^ (srow & 7);
  const __bf16* kSrcBase = Kg + (bT + srow) * C_ + h * 64 + schunk * 8;
  const __bf16* vSrcBase = Vtg + (long)(h * 64 + srow) * BT_ + bT + schunk * 8;
  __bf16* kDst = &Ks[0][tid * 8];
  __bf16* vDst = &Vs[0][tid * 8];
  const int bufStride = 64 * 64;

  bf16x8 q0s, q1s;
  {
    bf16x8 r0 = *(const bf16x8*)(Qg + (bT + q_lane) * C_ + h * 64 + qtr * 8);
    bf16x8 r1 = *(const bf16x8*)(Qg + (bT + q_lane) * C_ + h * 64 + 32 + qtr * 8);
#pragma unroll
    for (int j = 0; j < 8; j++) {
      q0s[j] = (__bf16)((float)r0[j] * 0.125f);
      q1s[j] = (__bf16)((float)r1[j] * 0.125f);
    }
  }

  f32x4 o[4] = {};
  float m_ = -1e30f, l_ = 0.0f;
  const int nkt = 2 * qx + 2;

  gload_lds16(kSrcBase, kDst);
  gload_lds16(vSrcBase, vDst);
  __syncthreads();

  int buf = 0;
  for (int t = 0; t < nkt; t++) {
    const int k0 = t * 64;
    if (t + 1 < nkt) {
      const long koff = (long)(k0 + 64);
      gload_lds16(kSrcBase + koff * C_, kDst + (buf ^ 1) * bufStride);
      gload_lds16(vSrcBase + koff, vDst + (buf ^ 1) * bufStride);
    }
    if (k0 <= qwTop) {
      const __bf16* ks = Ks[buf];
      const __bf16* vs = Vs[buf];
      f32x4 sT[4] = {};
      __builtin_amdgcn_s_setprio(1);
#pragma unroll
      for (int kb = 0; kb < 4; kb++) {
        bf16x8 aK0 = *(const bf16x8*)&ks[(kb * 16 + l15) * 64 + ((qtr ^ (l15 & 7)) * 8)];
        bf16x8 aK1 = *(const bf16x8*)&ks[(kb * 16 + l15) * 64 + (((4 + qtr) ^ (l15 & 7)) * 8)];
        sT[kb] = __builtin_amdgcn_mfma_f32_16x16x32_bf16(aK0, q0s, sT[kb], 0, 0, 0);
        sT[kb] = __builtin_amdgcn_mfma_f32_16x16x32_bf16(aK1, q1s, sT[kb], 0, 0, 0);
      }
      __builtin_amdgcn_s_setprio(0);
      if (k0 + 63 > qw) {
#pragma unroll
        for (int kb = 0; kb < 4; kb++)
#pragma unroll
          for (int r = 0; r < 4; r++)
            if (k0 + kb * 16 + qtr * 4 + r > q_lane) sT[kb][r] = -1e30f;
      }
      float mx = -1e30f;
#pragma unroll
      for (int kb = 0; kb < 4; kb++)
#pragma unroll
        for (int r = 0; r < 4; r++) mx = fmaxf(mx, sT[kb][r]);
      mx = fmaxf(mx, __shfl_xor(mx, 16));
      mx = fmaxf(mx, __shfl_xor(mx, 32));
      const float mnew = fmaxf(m_, mx);
      const float fac = __expf(m_ - mnew);
      float psum = 0.0f;
#pragma unroll
      for (int kb = 0; kb < 4; kb++)
#pragma unroll
        for (int r = 0; r < 4; r++) {
          const float pv = __expf(sT[kb][r] - mnew);
          psum += pv;
          Ps[(wid * 16 + l15) * PSTR + kb * 16 + qtr * 4 + r] = (__bf16)pv;
        }
      psum += __shfl_xor(psum, 16);
      psum += __shfl_xor(psum, 32);
      l_ = l_ * fac + psum;
      m_ = mnew;
#pragma unroll
      for (int r = 0; r < 4; r++) {
        const float fr = __shfl(fac, (lane & 48) + qtr * 4 + r);
#pragma unroll
        for (int dg = 0; dg < 4; dg++) o[dg][r] *= fr;
      }
      __builtin_amdgcn_s_setprio(1);
#pragma unroll
      for (int s = 0; s < 2; s++) {
        bf16x8 aP = *(const bf16x8*)&Ps[(wid * 16 + l15) * PSTR + s * 32 + qtr * 8];
#pragma unroll
        for (int dg = 0; dg < 4; dg++) {
          bf16x8 bV = *(const bf16x8*)&vs[(dg * 16 + l15) * 64 + (((s * 4 + qtr) ^ (l15 & 7)) * 8)];
          o[dg] = __builtin_amdgcn_mfma_f32_16x16x32_bf16(aP, bV, o[dg], 0, 0, 0);
        }
      }
      __builtin_amdgcn_s_setprio(0);
    }
    __syncthreads();
    buf ^= 1;
  }

  const float linv = 1.0f / l_;
#pragma unroll
  for (int r = 0; r < 4; r++) {
    const float lr = __shfl(linv, (lane & 48) + qtr * 4 + r);
    const long row = bT + qw + qtr * 4 + r;
#pragma unroll
    for (int dg = 0; dg < 4; dg++)
      O[row * C_ + h * 64 + dg * 16 + l15] = (__bf16)(o[dg][r] * lr);
  }
}

// ---------------- launch ----------------
extern "C" void kernel_launch(void* const* d_in, const int* in_sizes, int n_in,
                              void* d_out, int out_size, void* d_ws, size_t ws_size,
                              hipStream_t stream) {
  const float* x = (const float*)d_in[0];
  const float* wq = (const float*)d_in[1];
  const float* wk = (const float*)d_in[2];
  const float* wv = (const float*)d_in[3];
  const float* wproj = (const float*)d_in[4];
  const float* bproj = (const float*)d_in[5];
  const float* w1 = (const float*)d_in[6];
  const float* b1 = (const float*)d_in[7];
  const float* w2 = (const float*)d_in[8];
  const float* b2 = (const float*)d_in[9];
  const float* g1 = (const float*)d_in[10];
  const float* be1 = (const float*)d_in[11];
  const float* g2 = (const float*)d_in[12];
  const float* be2 = (const float*)d_in[13];

  char* ws = (char*)d_ws;
  const size_t MB = 1024ull * 1024ull;
  __bf16* h1 = (__bf16*)(ws + 0);          // 16MB; reused as att after QKV
  __bf16* Qb = (__bf16*)(ws + 16 * MB);    // 16MB; reused as h2 after attn
  __bf16* Kb = (__bf16*)(ws + 32 * MB);    // 16MB
  __bf16* Vtg = (__bf16*)(ws + 48 * MB);   // 16MB, V pre-transposed [C][B*T]
  __bf16* ff1 = (__bf16*)(ws + 32 * MB);   // 64MB, aliases Kb/Vtg (dead after attn)
  __bf16* wqt = (__bf16*)(ws + 96 * MB);   // wqt/wkt/wvt contiguous => [3072][1024]
  __bf16* wkt = (__bf16*)(ws + 98 * MB);
  __bf16* wvt = (__bf16*)(ws + 100 * MB);
  __bf16* wpt = (__bf16*)(ws + 102 * MB);
  __bf16* w1t = (__bf16*)(ws + 104 * MB);  // 8MB
  __bf16* w2t = (__bf16*)(ws + 112 * MB);  // 8MB
  __bf16* att = h1;
  __bf16* h2 = Qb;
  float* xout = (float*)d_out;

  dim3 tb(32, 8);
  transpose_f32_bf16<<<dim3(2, 32, 16), tb, 0, stream>>>(wq, wqt, 1024, 64, 1024 * 64, 64 * 1024);
  transpose_f32_bf16<<<dim3(2, 32, 16), tb, 0, stream>>>(wk, wkt, 1024, 64, 1024 * 64, 64 * 1024);
  transpose_f32_bf16<<<dim3(2, 32, 16), tb, 0, stream>>>(wv, wvt, 1024, 64, 1024 * 64, 64 * 1024);
  transpose_f32_bf16<<<dim3(32, 32, 1), tb, 0, stream>>>(wproj, wpt, 1024, 1024, 0, 0);
  transpose_f32_bf16<<<dim3(128, 32, 1), tb, 0, stream>>>(w1, w1t, 1024, 4096, 0, 0);
  transpose_f32_bf16<<<dim3(32, 128, 1), tb, 0, stream>>>(w2, w2t, 4096, 1024, 0, 0);

  ln_fwd<<<8192, 256, 0, stream>>>(x, g1, be1, h1);
  // fused QKV: Bt = [wqt|wkt|wvt] = [3072][1024]
  gemm256<1><<<dim3(12, 32), 512, 0, stream>>>(h1, wqt, Qb, Kb, Vtg, nullptr, 8192, 3072, 1024);
  attn_fwd2<<<dim3(16, 64), 512, 0, stream>>>(Qb, Kb, Vtg, att);
  gemm_bt<0, 0, 1, 1, 0><<<dim3(8, 64), 256, 0, stream>>>(att, wpt, xout, bproj, x, 8192, 1024, 1024);
  ln_fwd<<<8192, 256, 0, stream>>>(xout, g2, be2, h2);
  gemm256<0><<<dim3(16, 32), 512, 0, stream>>>(h2, w1t, ff1, nullptr, nullptr, b1, 8192, 4096, 1024);
  gemm_bt<0, 0, 1, 1, 0><<<dim3(8, 64), 256, 0, stream>>>(ff1, w2t, xout, b2, (const float*)xout, 8192, 1024, 4096);
}

// Round 4
// 392.931 us; speedup vs baseline: 1.9726x; 1.1894x over previous
//
#include <hip/hip_runtime.h>

// Block: LN1 -> per-head QKV -> causal attn -> proj+resid -> LN2 -> FF(relu)+resid
// B=4, T=2048, C=1024, H=16, HD=64.  All GEMMs bf16 MFMA (16x16x32), fp32 accum.

#define B_ 4
#define T_ 2048
#define C_ 1024
#define H_ 16
#define BT_ 8192

typedef __attribute__((ext_vector_type(8))) __bf16 bf16x8;
typedef __attribute__((ext_vector_type(4))) __bf16 bf16x4;
typedef __attribute__((ext_vector_type(4))) float f32x4;

#define WAIT_LGKM0 asm volatile("s_waitcnt lgkmcnt(0)" ::: "memory")
#define WAIT_VM(N) asm volatile("s_waitcnt vmcnt(" #N ")" ::: "memory")

__device__ __forceinline__ void gload_lds16(const void* g, void* l) {
  __builtin_amdgcn_global_load_lds((const __attribute__((address_space(1))) void*)g,
                                   (__attribute__((address_space(3))) void*)l, 16, 0, 0);
}

__device__ __forceinline__ void block_sync() {
  asm volatile("" ::: "memory");
  __builtin_amdgcn_s_barrier();
  asm volatile("" ::: "memory");
}

// ---------------- transpose fp32 [R][Cc] -> bf16 [Cc][R], batched ----------------
__global__ __launch_bounds__(256) void transpose_f32_bf16(
    const float* __restrict__ in, __bf16* __restrict__ out,
    int R, int Cc, long inBatch, long outBatch) {
  __shared__ float tile[32][33];
  const int tx = threadIdx.x, ty = threadIdx.y;
  in += (long)blockIdx.z * inBatch;
  out += (long)blockIdx.z * outBatch;
  const int r0 = blockIdx.y * 32, c0 = blockIdx.x * 32;
#pragma unroll
  for (int i = 0; i < 4; i++)
    tile[ty + i * 8][tx] = in[(long)(r0 + ty + i * 8) * Cc + c0 + tx];
  __syncthreads();
#pragma unroll
  for (int i = 0; i < 4; i++)
    out[(long)(c0 + ty + i * 8) * R + r0 + tx] = (__bf16)tile[tx][ty + i * 8];
}

// ---------------- LayerNorm: fp32 [rows][1024] -> bf16 ----------------
__global__ __launch_bounds__(256) void ln_fwd(const float* __restrict__ x,
                                              const float* __restrict__ g,
                                              const float* __restrict__ bta,
                                              __bf16* __restrict__ out) {
  const long row = blockIdx.x;
  const int tid = threadIdx.x;
  float4 v = ((const float4*)(x + row * C_))[tid];
  float vals[4] = {v.x, v.y, v.z, v.w};
  float s = vals[0] + vals[1] + vals[2] + vals[3];
  float s2 = vals[0] * vals[0] + vals[1] * vals[1] + vals[2] * vals[2] + vals[3] * vals[3];
#pragma unroll
  for (int o = 1; o < 64; o <<= 1) {
    s += __shfl_xor(s, o);
    s2 += __shfl_xor(s2, o);
  }
  __shared__ float red[8];
  const int lane = tid & 63, wid = tid >> 6;
  if (lane == 0) { red[wid] = s; red[wid + 4] = s2; }
  __syncthreads();
  const float S = red[0] + red[1] + red[2] + red[3];
  const float S2 = red[4] + red[5] + red[6] + red[7];
  const float mu = S * (1.0f / C_);
  const float var = S2 * (1.0f / C_) - mu * mu;
  const float rs = rsqrtf(var + 1e-5f);
  bf16x4 o4;
#pragma unroll
  for (int j = 0; j < 4; j++) {
    const int c = tid * 4 + j;
    o4[j] = (__bf16)((vals[j] - mu) * rs * g[c] + bta[c]);
  }
  *(bf16x4*)(out + row * C_ + tid * 4) = o4;
}

// ---------------- GEMM: BM x 256 tile, 3-slot ring, counted vmcnt ----------------
// A[M,K] x Bt[N,K]. 512 thr = 8 waves (2M x 4N). BM=256: per-wave 128x64 (2 phases);
// BM=128: per-wave 64x64 (1 phase). LDS = 3*(BM+256)*32*2B (96KB / 72KB).
// Chunk swizzle pos = chunk ^ ((row>>1)&3), staged via pre-swizzled global source.
// EPI 0: bf16 out, bias+relu (FF1). EPI 1: QKV routing. EPI 2: fp32 out, bias+resid.
template <int BM, int EPI>
__global__ __launch_bounds__(512, 2) void gemm_mt(
    const __bf16* __restrict__ A, const __bf16* __restrict__ Bt,
    void* out0, void* out1, void* out2,
    const float* __restrict__ bias, const float* __restrict__ resid,
    int M, int N, int K) {
  constexpr int SLOT = (BM + 256) * 32;  // elements per ring slot
  constexpr int ASZ = BM * 32;           // A elements per slot
  constexpr int RF = BM / 32;            // row frags per wave (8 or 4)
  constexpr int WROW = BM / 2;           // rows per wave
  __shared__ __bf16 sm[3 * SLOT];
  const int tid = threadIdx.x, lane = tid & 63, wid = tid >> 6;
  const int wm = wid >> 2, wn = wid & 3;
  const int l15 = lane & 15, qtr = lane >> 4;
  const long mBase = (long)blockIdx.y * BM, nBase = (long)blockIdx.x * 256;
  const int NT = K >> 5;

  f32x4 acc[RF][4] = {};

  const int posOff = (qtr ^ ((l15 >> 1) & 3)) * 8;
  const int aBase = (wm * WROW + l15) * 32 + posOff;
  const int bBase = (wn * 64 + l15) * 32 + posOff;

  const int trow = tid >> 2;
  const long coff = (long)(((tid & 3) ^ ((tid >> 3) & 3)) * 8);
  const __bf16* aS0 = A + (mBase + trow) * (long)K + coff;
  const __bf16* aS1 = aS0 + 128 * (long)K;  // BM==256 only
  const __bf16* bS0 = Bt + (nBase + trow) * (long)K + coff;
  const __bf16* bS1 = bS0 + 128 * (long)K;

  // prologue: stage tiles 0,1 into slots 0,1
#pragma unroll
  for (int p = 0; p < 2; p++) {
    __bf16* d = &sm[p * SLOT];
    const long kc = (long)p * 32;
    gload_lds16(aS0 + kc, d + tid * 8);
    if (BM == 256) gload_lds16(aS1 + kc, d + 4096 + tid * 8);
    gload_lds16(bS0 + kc, d + ASZ + tid * 8);
    gload_lds16(bS1 + kc, d + ASZ + 4096 + tid * 8);
  }
  if (BM == 256) WAIT_VM(4); else WAIT_VM(3);
  block_sync();

  int sl = 0;
  for (int t = 0; t < NT; ++t) {
    const __bf16* sA = &sm[sl * SLOT];
    const __bf16* sB = sA + ASZ;
    const int slN = (sl + 2 >= 3) ? sl - 1 : sl + 2;
    __bf16* stA = &sm[slN * SLOT];
    __bf16* stB = stA + ASZ;
    const long kc = (long)(t + 2) * 32;
    const bool doStage = (t + 2 < NT);

    bf16x8 bfr[4], af[4];
#pragma unroll
    for (int cf = 0; cf < 4; cf++) bfr[cf] = *(const bf16x8*)&sB[bBase + cf * 512];
#pragma unroll
    for (int rf = 0; rf < 4; rf++) af[rf] = *(const bf16x8*)&sA[aBase + rf * 512];

    if (BM == 256) {
      // ---- phase 0: MFMA rf0-3; stage next A
      if (doStage) {
        gload_lds16(aS0 + kc, stA + tid * 8);
        gload_lds16(aS1 + kc, stA + 4096 + tid * 8);
      }
      block_sync();
      WAIT_LGKM0;
      __builtin_amdgcn_s_setprio(1);
#pragma unroll
      for (int rf = 0; rf < 4; rf++)
#pragma unroll
        for (int cf = 0; cf < 4; cf++)
          acc[rf][cf] = __builtin_amdgcn_mfma_f32_16x16x32_bf16(af[rf], bfr[cf], acc[rf][cf], 0, 0, 0);
      __builtin_amdgcn_s_setprio(0);
      block_sync();
      // ---- phase 1: MFMA rf4-7; stage next B
#pragma unroll
      for (int rf = 0; rf < 4; rf++) af[rf] = *(const bf16x8*)&sA[aBase + 2048 + rf * 512];
      if (doStage) {
        gload_lds16(bS0 + kc, stB + tid * 8);
        gload_lds16(bS1 + kc, stB + 4096 + tid * 8);
        WAIT_VM(4);
      } else {
        WAIT_VM(0);
      }
      block_sync();
      WAIT_LGKM0;
      __builtin_amdgcn_s_setprio(1);
#pragma unroll
      for (int rf = 0; rf < 4; rf++)
#pragma unroll
        for (int cf = 0; cf < 4; cf++)
          acc[(RF == 8 ? 4 : 0) + rf][cf] =
              __builtin_amdgcn_mfma_f32_16x16x32_bf16(af[rf], bfr[cf], acc[(RF == 8 ? 4 : 0) + rf][cf], 0, 0, 0);
      __builtin_amdgcn_s_setprio(0);
      block_sync();
    } else {
      // ---- single phase: 16 MFMA; stage next A+B
      if (doStage) {
        gload_lds16(aS0 + kc, stA + tid * 8);
        gload_lds16(bS0 + kc, stB + tid * 8);
        gload_lds16(bS1 + kc, stB + 4096 + tid * 8);
        WAIT_VM(3);
      } else {
        WAIT_VM(0);
      }
      block_sync();
      WAIT_LGKM0;
      __builtin_amdgcn_s_setprio(1);
#pragma unroll
      for (int rf = 0; rf < 4; rf++)
#pragma unroll
        for (int cf = 0; cf < 4; cf++)
          acc[rf][cf] = __builtin_amdgcn_mfma_f32_16x16x32_bf16(af[rf], bfr[cf], acc[rf][cf], 0, 0, 0);
      __builtin_amdgcn_s_setprio(0);
      block_sync();
    }
    sl = (sl + 1 == 3) ? 0 : sl + 1;
  }

  // ---- epilogue
  if (EPI == 0) {
    __bf16* outB = (__bf16*)out0;
#pragma unroll
    for (int cf = 0; cf < 4; cf++) {
      const long gc = nBase + wn * 64 + cf * 16 + l15;
      const float bv = bias[gc];
#pragma unroll
      for (int rfi = 0; rfi < RF; rfi++) {
        const long gr0 = mBase + wm * WROW + rfi * 16 + qtr * 4;
#pragma unroll
        for (int r = 0; r < 4; r++)
          outB[(gr0 + r) * (long)N + gc] = (__bf16)fmaxf(acc[rfi][cf][r] + bv, 0.0f);
      }
    }
  } else if (EPI == 2) {
    float* outF = (float*)out0;
#pragma unroll
    for (int cf = 0; cf < 4; cf++) {
      const long gc = nBase + wn * 64 + cf * 16 + l15;
      const float bv = bias[gc];
#pragma unroll
      for (int rfi = 0; rfi < RF; rfi++) {
        const long gr0 = mBase + wm * WROW + rfi * 16 + qtr * 4;
#pragma unroll
        for (int r = 0; r < 4; r++)
          outF[(gr0 + r) * (long)N + gc] = acc[rfi][cf][r] + bv + resid[(gr0 + r) * (long)N + gc];
      }
    }
  } else {
    // QKV routing: seg 0 -> Q [BT,1024], 1 -> K [BT,1024], 2 -> V transposed [1024][BT]
    const int seg = (int)(nBase >> 10);
#pragma unroll
    for (int cf = 0; cf < 4; cf++) {
      const long gc = nBase + wn * 64 + cf * 16 + l15;
      const long cc = gc & 1023;
#pragma unroll
      for (int rfi = 0; rfi < RF; rfi++) {
        const long gr0 = mBase + wm * WROW + rfi * 16 + qtr * 4;
        if (seg == 0) {
          __bf16* Qb = (__bf16*)out0;
#pragma unroll
          for (int r = 0; r < 4; r++) Qb[(gr0 + r) * 1024 + cc] = (__bf16)acc[rfi][cf][r];
        } else if (seg == 1) {
          __bf16* Kb = (__bf16*)out1;
#pragma unroll
          for (int r = 0; r < 4; r++) Kb[(gr0 + r) * 1024 + cc] = (__bf16)acc[rfi][cf][r];
        } else {
          __bf16* Vtg = (__bf16*)out2;
          bf16x4 v4;
#pragma unroll
          for (int r = 0; r < 4; r++) v4[r] = (__bf16)acc[rfi][cf][r];
          *(bf16x4*)&Vtg[cc * (long)BT_ + gr0] = v4;
        }
      }
    }
  }
}

// ---------------- causal flash attention v2 ----------------
// grid (B*H, 16): blockIdx.x = bh so all q-blocks of a head share an XCD (wgid%8).
// log2-domain softmax (Q pre-scaled by 0.125*log2e); defer-max (T13, THR=8).
#define PSTR 72
__global__ __launch_bounds__(512, 6) void attn_fwd2(
    const __bf16* __restrict__ Qg, const __bf16* __restrict__ Kg,
    const __bf16* __restrict__ Vtg, __bf16* __restrict__ O) {
  __shared__ __bf16 Ks[2][64 * 64];
  __shared__ __bf16 Vs[2][64 * 64];
  __shared__ __bf16 Ps[128 * PSTR];
  const int tid = threadIdx.x, lane = tid & 63, wid = tid >> 6;
  const int bh = blockIdx.x, b = bh >> 4, h = bh & 15;
  const int qx = 15 - blockIdx.y;           // heavy blocks first
  const int qBase = qx * 128;
  const int qw = qBase + wid * 16;
  const int qwTop = qw + 15;
  const long bT = (long)b * T_;
  const int l15 = lane & 15, qtr = lane >> 4;
  const int q_lane = qw + l15;

  const int srow = tid >> 3;
  const int schunk = (tid & 7) ^ (srow & 7);
  const __bf16* kSrcBase = Kg + (bT + srow) * C_ + h * 64 + schunk * 8;
  const __bf16* vSrcBase = Vtg + (long)(h * 64 + srow) * BT_ + bT + schunk * 8;
  __bf16* kDst = &Ks[0][tid * 8];
  __bf16* vDst = &Vs[0][tid * 8];
  const int bufStride = 64 * 64;

  bf16x8 q0s, q1s;
  {
    const float SC = 0.125f * 1.44269504089f;  // 1/sqrt(64) * log2(e)
    bf16x8 r0 = *(const bf16x8*)(Qg + (bT + q_lane) * C_ + h * 64 + qtr * 8);
    bf16x8 r1 = *(const bf16x8*)(Qg + (bT + q_lane) * C_ + h * 64 + 32 + qtr * 8);
#pragma unroll
    for (int j = 0; j < 8; j++) {
      q0s[j] = (__bf16)((float)r0[j] * SC);
      q1s[j] = (__bf16)((float)r1[j] * SC);
    }
  }

  f32x4 o[4] = {};
  float m_ = -1e30f, l_ = 0.0f;
  const int nkt = 2 * qx + 2;

  gload_lds16(kSrcBase, kDst);
  gload_lds16(vSrcBase, vDst);
  __syncthreads();

  int buf = 0;
  for (int t = 0; t < nkt; t++) {
    const int k0 = t * 64;
    if (t + 1 < nkt) {
      const long koff = (long)(k0 + 64);
      gload_lds16(kSrcBase + koff * C_, kDst + (buf ^ 1) * bufStride);
      gload_lds16(vSrcBase + koff, vDst + (buf ^ 1) * bufStride);
    }
    if (k0 <= qwTop) {
      const __bf16* ks = Ks[buf];
      const __bf16* vs = Vs[buf];
      f32x4 sT[4] = {};
      __builtin_amdgcn_s_setprio(1);
#pragma unroll
      for (int kb = 0; kb < 4; kb++) {
        bf16x8 aK0 = *(const bf16x8*)&ks[(kb * 16 + l15) * 64 + ((qtr ^ (l15 & 7)) * 8)];
        bf16x8 aK1 = *(const bf16x8*)&ks[(kb * 16 + l15) * 64 + (((4 + qtr) ^ (l15 & 7)) * 8)];
        sT[kb] = __builtin_amdgcn_mfma_f32_16x16x32_bf16(aK0, q0s, sT[kb], 0, 0, 0);
        sT[kb] = __builtin_amdgcn_mfma_f32_16x16x32_bf16(aK1, q1s, sT[kb], 0, 0, 0);
      }
      __builtin_amdgcn_s_setprio(0);
      if (k0 + 63 > qw) {
#pragma unroll
        for (int kb = 0; kb < 4; kb++)
#pragma unroll
          for (int r = 0; r < 4; r++)
            if (k0 + kb * 16 + qtr * 4 + r > q_lane) sT[kb][r] = -1e30f;
      }
      float mx = -1e30f;
#pragma unroll
      for (int kb = 0; kb < 4; kb++)
#pragma unroll
        for (int r = 0; r < 4; r++) mx = fmaxf(mx, sT[kb][r]);
      mx = fmaxf(mx, __shfl_xor(mx, 16));
      mx = fmaxf(mx, __shfl_xor(mx, 32));
      // defer-max: skip rescale when no row grew by > 8 (log2 units; P <= 256)
      const bool defer = __all(mx - m_ <= 8.0f);
      const float mnew = defer ? m_ : fmaxf(m_, mx);
      float psum = 0.0f;
#pragma unroll
      for (int kb = 0; kb < 4; kb++)
#pragma unroll
        for (int r = 0; r < 4; r++) {
          const float pv = exp2f(sT[kb][r] - mnew);
          psum += pv;
          Ps[(wid * 16 + l15) * PSTR + kb * 16 + qtr * 4 + r] = (__bf16)pv;
        }
      psum += __shfl_xor(psum, 16);
      psum += __shfl_xor(psum, 32);
      if (defer) {
        l_ += psum;
      } else {
        const float fac = exp2f(m_ - mnew);
        l_ = l_ * fac + psum;
        m_ = mnew;
#pragma unroll
        for (int r = 0; r < 4; r++) {
          const float fr = __shfl(fac, (lane & 48) + qtr * 4 + r);
#pragma unroll
          for (int dg = 0; dg < 4; dg++) o[dg][r] *= fr;
        }
      }
      __builtin_amdgcn_s_setprio(1);
#pragma unroll
      for (int s = 0; s < 2; s++) {
        bf16x8 aP = *(const bf16x8*)&Ps[(wid * 16 + l15) * PSTR + s * 32 + qtr * 8];
#pragma unroll
        for (int dg = 0; dg < 4; dg++) {
          bf16x8 bV = *(const bf16x8*)&vs[(dg * 16 + l15) * 64 + (((s * 4 + qtr) ^ (l15 & 7)) * 8)];
          o[dg] = __builtin_amdgcn_mfma_f32_16x16x32_bf16(aP, bV, o[dg], 0, 0, 0);
        }
      }
      __builtin_amdgcn_s_setprio(0);
    }
    __syncthreads();
    buf ^= 1;
  }

  const float linv = 1.0f / l_;
#pragma unroll
  for (int r = 0; r < 4; r++) {
    const float lr = __shfl(linv, (lane & 48) + qtr * 4 + r);
    const long row = bT + qw + qtr * 4 + r;
#pragma unroll
    for (int dg = 0; dg < 4; dg++)
      O[row * C_ + h * 64 + dg * 16 + l15] = (__bf16)(o[dg][r] * lr);
  }
}

// ---------------- launch ----------------
extern "C" void kernel_launch(void* const* d_in, const int* in_sizes, int n_in,
                              void* d_out, int out_size, void* d_ws, size_t ws_size,
                              hipStream_t stream) {
  const float* x = (const float*)d_in[0];
  const float* wq = (const float*)d_in[1];
  const float* wk = (const float*)d_in[2];
  const float* wv = (const float*)d_in[3];
  const float* wproj = (const float*)d_in[4];
  const float* bproj = (const float*)d_in[5];
  const float* w1 = (const float*)d_in[6];
  const float* b1 = (const float*)d_in[7];
  const float* w2 = (const float*)d_in[8];
  const float* b2 = (const float*)d_in[9];
  const float* g1 = (const float*)d_in[10];
  const float* be1 = (const float*)d_in[11];
  const float* g2 = (const float*)d_in[12];
  const float* be2 = (const float*)d_in[13];

  char* ws = (char*)d_ws;
  const size_t MB = 1024ull * 1024ull;
  __bf16* h1 = (__bf16*)(ws + 0);          // 16MB; reused as att after QKV
  __bf16* Qb = (__bf16*)(ws + 16 * MB);    // 16MB; reused as h2 after attn
  __bf16* Kb = (__bf16*)(ws + 32 * MB);    // 16MB
  __bf16* Vtg = (__bf16*)(ws + 48 * MB);   // 16MB, V pre-transposed [C][B*T]
  __bf16* ff1 = (__bf16*)(ws + 32 * MB);   // 64MB, aliases Kb/Vtg (dead after attn)
  __bf16* wqt = (__bf16*)(ws + 96 * MB);   // wqt/wkt/wvt contiguous => [3072][1024]
  __bf16* wkt = (__bf16*)(ws + 98 * MB);
  __bf16* wvt = (__bf16*)(ws + 100 * MB);
  __bf16* wpt = (__bf16*)(ws + 102 * MB);
  __bf16* w1t = (__bf16*)(ws + 104 * MB);  // 8MB
  __bf16* w2t = (__bf16*)(ws + 112 * MB);  // 8MB
  __bf16* att = h1;
  __bf16* h2 = Qb;
  float* xout = (float*)d_out;

  dim3 tb(32, 8);
  transpose_f32_bf16<<<dim3(2, 32, 16), tb, 0, stream>>>(wq, wqt, 1024, 64, 1024 * 64, 64 * 1024);
  transpose_f32_bf16<<<dim3(2, 32, 16), tb, 0, stream>>>(wk, wkt, 1024, 64, 1024 * 64, 64 * 1024);
  transpose_f32_bf16<<<dim3(2, 32, 16), tb, 0, stream>>>(wv, wvt, 1024, 64, 1024 * 64, 64 * 1024);
  transpose_f32_bf16<<<dim3(32, 32, 1), tb, 0, stream>>>(wproj, wpt, 1024, 1024, 0, 0);
  transpose_f32_bf16<<<dim3(128, 32, 1), tb, 0, stream>>>(w1, w1t, 1024, 4096, 0, 0);
  transpose_f32_bf16<<<dim3(32, 128, 1), tb, 0, stream>>>(w2, w2t, 4096, 1024, 0, 0);

  ln_fwd<<<8192, 256, 0, stream>>>(x, g1, be1, h1);
  // fused QKV: Bt = [wqt|wkt|wvt] = [3072][1024]; BM=128 => 768 blocks (3/CU)
  gemm_mt<128, 1><<<dim3(12, 64), 512, 0, stream>>>(h1, wqt, Qb, Kb, Vtg, nullptr, nullptr, 8192, 3072, 1024);
  attn_fwd2<<<dim3(64, 16), 512, 0, stream>>>(Qb, Kb, Vtg, att);
  gemm_mt<128, 2><<<dim3(4, 64), 512, 0, stream>>>(att, wpt, xout, nullptr, nullptr, bproj, x, 8192, 1024, 1024);
  ln_fwd<<<8192, 256, 0, stream>>>(xout, g2, be2, h2);
  gemm_mt<256, 0><<<dim3(16, 32), 512, 0, stream>>>(h2, w1t, ff1, nullptr, nullptr, b1, nullptr, 8192, 4096, 1024);
  gemm_mt<128, 2><<<dim3(4, 64), 512, 0, stream>>>(ff1, w2t, xout, nullptr, nullptr, b2, (const float*)xout, 8192, 1024, 4096);
}

// Round 5
// 383.828 us; speedup vs baseline: 2.0194x; 1.0237x over previous
//
#include <hip/hip_runtime.h>

// Block: LN1 -> per-head QKV -> causal attn -> proj+resid -> LN2 -> FF(relu)+resid
// B=4, T=2048, C=1024, H=16, HD=64.  All GEMMs bf16 MFMA (16x16x32), fp32 accum.

#define B_ 4
#define T_ 2048
#define C_ 1024
#define H_ 16
#define BT_ 8192

typedef __attribute__((ext_vector_type(8))) __bf16 bf16x8;
typedef __attribute__((ext_vector_type(4))) __bf16 bf16x4;
typedef __attribute__((ext_vector_type(4))) float f32x4;

#define WAIT_LGKM0 asm volatile("s_waitcnt lgkmcnt(0)" ::: "memory")
#define WAIT_VM(N) asm volatile("s_waitcnt vmcnt(" #N ")" ::: "memory")

__device__ __forceinline__ void gload_lds16(const void* g, void* l) {
  __builtin_amdgcn_global_load_lds((const __attribute__((address_space(1))) void*)g,
                                   (__attribute__((address_space(3))) void*)l, 16, 0, 0);
}

__device__ __forceinline__ void block_sync() {
  asm volatile("" ::: "memory");
  __builtin_amdgcn_s_barrier();
  asm volatile("" ::: "memory");
}

// ---------------- transpose fp32 [R][Cc] -> bf16 [Cc][R], batched ----------------
__global__ __launch_bounds__(256) void transpose_f32_bf16(
    const float* __restrict__ in, __bf16* __restrict__ out,
    int R, int Cc, long inBatch, long outBatch) {
  __shared__ float tile[32][33];
  const int tx = threadIdx.x, ty = threadIdx.y;
  in += (long)blockIdx.z * inBatch;
  out += (long)blockIdx.z * outBatch;
  const int r0 = blockIdx.y * 32, c0 = blockIdx.x * 32;
#pragma unroll
  for (int i = 0; i < 4; i++)
    tile[ty + i * 8][tx] = in[(long)(r0 + ty + i * 8) * Cc + c0 + tx];
  __syncthreads();
#pragma unroll
  for (int i = 0; i < 4; i++)
    out[(long)(c0 + ty + i * 8) * R + r0 + tx] = (__bf16)tile[tx][ty + i * 8];
}

// ---------------- LayerNorm: fp32 [rows][1024] -> bf16 ----------------
__global__ __launch_bounds__(256) void ln_fwd(const float* __restrict__ x,
                                              const float* __restrict__ g,
                                              const float* __restrict__ bta,
                                              __bf16* __restrict__ out) {
  const long row = blockIdx.x;
  const int tid = threadIdx.x;
  float4 v = ((const float4*)(x + row * C_))[tid];
  float vals[4] = {v.x, v.y, v.z, v.w};
  float s = vals[0] + vals[1] + vals[2] + vals[3];
  float s2 = vals[0] * vals[0] + vals[1] * vals[1] + vals[2] * vals[2] + vals[3] * vals[3];
#pragma unroll
  for (int o = 1; o < 64; o <<= 1) {
    s += __shfl_xor(s, o);
    s2 += __shfl_xor(s2, o);
  }
  __shared__ float red[8];
  const int lane = tid & 63, wid = tid >> 6;
  if (lane == 0) { red[wid] = s; red[wid + 4] = s2; }
  __syncthreads();
  const float S = red[0] + red[1] + red[2] + red[3];
  const float S2 = red[4] + red[5] + red[6] + red[7];
  const float mu = S * (1.0f / C_);
  const float var = S2 * (1.0f / C_) - mu * mu;
  const float rs = rsqrtf(var + 1e-5f);
  bf16x4 o4;
#pragma unroll
  for (int j = 0; j < 4; j++) {
    const int c = tid * 4 + j;
    o4[j] = (__bf16)((vals[j] - mu) * rs * g[c] + bta[c]);
  }
  *(bf16x4*)(out + row * C_ + tid * 4) = o4;
}

// ---------------- GEMM 8-phase: 128x256 tile, BK=64, deep-pipelined ----------------
// A[M,K] x Bt[N,K]. 512 thr = 8 waves (2M x 4N), per-wave 64x64 (4rf x 4cf).
// LDS 96KB: A[2buf][2kh][128x32] + B[2buf][2kh][256x32].
// Per phase: 8 ds_read_b128; stage 3 gload_lds (slots freed at prev closing barrier,
// tile cur+2); counted vmcnt(6); mid-barrier; lgkmcnt0; 16 MFMA (setprio); closing barrier.
// Chunk swizzle pos^=((row>>1)&3) on both stage-source and ds_read (0 conflicts measured).
// EPI 0: bf16 bias+relu. EPI 1: QKV routing (V transposed). EPI 2: fp32 bias+resid.
template <int EPI>
__global__ __launch_bounds__(512, 2) void gemm8p(
    const __bf16* __restrict__ A, const __bf16* __restrict__ Bt,
    void* out0, void* out1, void* out2,
    const float* __restrict__ bias, const float* __restrict__ resid,
    int M, int N, int K, int nwg) {
  __shared__ __bf16 sm[49152];
  __bf16* ldsA = &sm[0];
  __bf16* ldsB = &sm[16384];
  const int tid = threadIdx.x, lane = tid & 63, wid = tid >> 6;
  const int wm = wid >> 2, wn = wid & 3;
  const int l15 = lane & 15, qtr = lane >> 4;
  // bijective chunked XCD swizzle (nwg % 8 == 0); m-fast decode => XCD shares B-panel
  const int q8 = nwg >> 3;
  const int wg = (blockIdx.x & 7) * q8 + (blockIdx.x >> 3);
  const int mBlocks = M >> 7;
  const long mBase = (long)(wg % mBlocks) * 128;
  const long nBase = (long)(wg / mBlocks) * 256;
  const int NT = K >> 6;

  f32x4 acc[4][4] = {};

  // staging source (pre-swizzled global chunk): row = tid>>2, pos = tid&3
  const int spos = (tid & 3) ^ ((tid >> 3) & 3);
  const __bf16* aS = A + (mBase + (tid >> 2)) * (long)K + spos * 8;
  const __bf16* bS0 = Bt + (nBase + (tid >> 2)) * (long)K + spos * 8;
  const __bf16* bS1 = bS0 + 128 * (long)K;

  // fragment-read offsets
  const int posRd = (qtr ^ ((l15 >> 1) & 3)) * 8;
  const int aRd = (wm * 64 + l15) * 32 + posRd;
  const int bRd = (wn * 64 + l15) * 32 + posRd;

#define STG_A(BUF, KT, KH) gload_lds16(aS + (KT) * 64 + (KH) * 32, ldsA + (BUF) * 8192 + (KH) * 4096 + tid * 8)
#define STG_B(BUF, KT, KH)                                                                    \
  do {                                                                                        \
    gload_lds16(bS0 + (KT) * 64 + (KH) * 32, ldsB + (BUF) * 16384 + (KH) * 8192 + tid * 8);   \
    gload_lds16(bS1 + (KT) * 64 + (KH) * 32, ldsB + (BUF) * 16384 + (KH) * 8192 + 4096 + tid * 8); \
  } while (0)

#define GPHASE(BUF, KH, VMN, ...)                                                          \
  do {                                                                                     \
    bf16x8 af0 = *(const bf16x8*)&ldsA[(BUF) * 8192 + (KH) * 4096 + aRd];                  \
    bf16x8 af1 = *(const bf16x8*)&ldsA[(BUF) * 8192 + (KH) * 4096 + aRd + 512];            \
    bf16x8 af2 = *(const bf16x8*)&ldsA[(BUF) * 8192 + (KH) * 4096 + aRd + 1024];           \
    bf16x8 af3 = *(const bf16x8*)&ldsA[(BUF) * 8192 + (KH) * 4096 + aRd + 1536];           \
    bf16x8 bf0 = *(const bf16x8*)&ldsB[(BUF) * 16384 + (KH) * 8192 + bRd];                 \
    bf16x8 bf1 = *(const bf16x8*)&ldsB[(BUF) * 16384 + (KH) * 8192 + bRd + 512];           \
    bf16x8 bf2 = *(const bf16x8*)&ldsB[(BUF) * 16384 + (KH) * 8192 + bRd + 1024];          \
    bf16x8 bf3 = *(const bf16x8*)&ldsB[(BUF) * 16384 + (KH) * 8192 + bRd + 1536];          \
    __VA_ARGS__;                                                                           \
    WAIT_VM(VMN);                                                                          \
    block_sync();                                                                          \
    WAIT_LGKM0;                                                                            \
    __builtin_amdgcn_sched_barrier(0);                                                     \
    __builtin_amdgcn_s_setprio(1);                                                         \
    acc[0][0] = __builtin_amdgcn_mfma_f32_16x16x32_bf16(af0, bf0, acc[0][0], 0, 0, 0);     \
    acc[0][1] = __builtin_amdgcn_mfma_f32_16x16x32_bf16(af0, bf1, acc[0][1], 0, 0, 0);     \
    acc[0][2] = __builtin_amdgcn_mfma_f32_16x16x32_bf16(af0, bf2, acc[0][2], 0, 0, 0);     \
    acc[0][3] = __builtin_amdgcn_mfma_f32_16x16x32_bf16(af0, bf3, acc[0][3], 0, 0, 0);     \
    acc[1][0] = __builtin_amdgcn_mfma_f32_16x16x32_bf16(af1, bf0, acc[1][0], 0, 0, 0);     \
    acc[1][1] = __builtin_amdgcn_mfma_f32_16x16x32_bf16(af1, bf1, acc[1][1], 0, 0, 0);     \
    acc[1][2] = __builtin_amdgcn_mfma_f32_16x16x32_bf16(af1, bf2, acc[1][2], 0, 0, 0);     \
    acc[1][3] = __builtin_amdgcn_mfma_f32_16x16x32_bf16(af1, bf3, acc[1][3], 0, 0, 0);     \
    acc[2][0] = __builtin_amdgcn_mfma_f32_16x16x32_bf16(af2, bf0, acc[2][0], 0, 0, 0);     \
    acc[2][1] = __builtin_amdgcn_mfma_f32_16x16x32_bf16(af2, bf1, acc[2][1], 0, 0, 0);     \
    acc[2][2] = __builtin_amdgcn_mfma_f32_16x16x32_bf16(af2, bf2, acc[2][2], 0, 0, 0);     \
    acc[2][3] = __builtin_amdgcn_mfma_f32_16x16x32_bf16(af2, bf3, acc[2][3], 0, 0, 0);     \
    acc[3][0] = __builtin_amdgcn_mfma_f32_16x16x32_bf16(af3, bf0, acc[3][0], 0, 0, 0);     \
    acc[3][1] = __builtin_amdgcn_mfma_f32_16x16x32_bf16(af3, bf1, acc[3][1], 0, 0, 0);     \
    acc[3][2] = __builtin_amdgcn_mfma_f32_16x16x32_bf16(af3, bf2, acc[3][2], 0, 0, 0);     \
    acc[3][3] = __builtin_amdgcn_mfma_f32_16x16x32_bf16(af3, bf3, acc[3][3], 0, 0, 0);     \
    __builtin_amdgcn_s_setprio(0);                                                         \
    block_sync();                                                                          \
  } while (0)

  // prologue: k0(0), k1(0), k0(1) = 9 loads; wait for k0(0)
  STG_A(0, 0, 0); STG_B(0, 0, 0);
  STG_A(0, 0, 1); STG_B(0, 0, 1);
  STG_A(1, 1, 0); STG_B(1, 1, 0);
  WAIT_VM(6);
  block_sync();

  // main: tiles (T, T+1), T = 0,2,..,NT-4
  for (int T = 0; T + 3 < NT; T += 2) {
    GPHASE(0, 0, 6, STG_A(1, T + 1, 1); STG_B(1, T + 1, 1));
    GPHASE(0, 1, 6, STG_A(0, T + 2, 0); STG_B(0, T + 2, 0));
    GPHASE(1, 0, 6, STG_A(0, T + 2, 1); STG_B(0, T + 2, 1));
    GPHASE(1, 1, 6, STG_A(1, T + 3, 0); STG_B(1, T + 3, 0));
  }
  // tail: tiles NT-2 (buf0), NT-1 (buf1)
  GPHASE(0, 0, 6, STG_A(1, NT - 1, 1); STG_B(1, NT - 1, 1));
  GPHASE(0, 1, 3, );
  GPHASE(1, 0, 0, );
  GPHASE(1, 1, 0, );

#undef GPHASE
#undef STG_A
#undef STG_B

  // ---- epilogue
  if (EPI == 0) {
    __bf16* outB = (__bf16*)out0;
#pragma unroll
    for (int cf = 0; cf < 4; cf++) {
      const long gc = nBase + wn * 64 + cf * 16 + l15;
      const float bv = bias[gc];
#pragma unroll
      for (int rf = 0; rf < 4; rf++) {
        const long gr0 = mBase + wm * 64 + rf * 16 + qtr * 4;
#pragma unroll
        for (int r = 0; r < 4; r++)
          outB[(gr0 + r) * (long)N + gc] = (__bf16)fmaxf(acc[rf][cf][r] + bv, 0.0f);
      }
    }
  } else if (EPI == 2) {
    float* outF = (float*)out0;
#pragma unroll
    for (int cf = 0; cf < 4; cf++) {
      const long gc = nBase + wn * 64 + cf * 16 + l15;
      const float bv = bias[gc];
#pragma unroll
      for (int rf = 0; rf < 4; rf++) {
        const long gr0 = mBase + wm * 64 + rf * 16 + qtr * 4;
#pragma unroll
        for (int r = 0; r < 4; r++)
          outF[(gr0 + r) * (long)N + gc] = acc[rf][cf][r] + bv + resid[(gr0 + r) * (long)N + gc];
      }
    }
  } else {
    // QKV routing: seg 0 -> Q [BT,1024], 1 -> K [BT,1024], 2 -> V transposed [1024][BT]
    const int seg = (int)(nBase >> 10);
#pragma unroll
    for (int cf = 0; cf < 4; cf++) {
      const long gc = nBase + wn * 64 + cf * 16 + l15;
      const long cc = gc & 1023;
#pragma unroll
      for (int rf = 0; rf < 4; rf++) {
        const long gr0 = mBase + wm * 64 + rf * 16 + qtr * 4;
        if (seg == 0) {
          __bf16* Qb = (__bf16*)out0;
#pragma unroll
          for (int r = 0; r < 4; r++) Qb[(gr0 + r) * 1024 + cc] = (__bf16)acc[rf][cf][r];
        } else if (seg == 1) {
          __bf16* Kb = (__bf16*)out1;
#pragma unroll
          for (int r = 0; r < 4; r++) Kb[(gr0 + r) * 1024 + cc] = (__bf16)acc[rf][cf][r];
        } else {
          __bf16* Vtg = (__bf16*)out2;
          bf16x4 v4;
#pragma unroll
          for (int r = 0; r < 4; r++) v4[r] = (__bf16)acc[rf][cf][r];
          *(bf16x4*)&Vtg[cc * (long)BT_ + gr0] = v4;
        }
      }
    }
  }
}

// ---------------- causal flash attention v2 ----------------
// grid (B*H, 16): blockIdx.x = bh so all q-blocks of a head share an XCD (wgid%8).
// log2-domain softmax (Q pre-scaled by 0.125*log2e); defer-max (T13, THR=8).
#define PSTR 72
__global__ __launch_bounds__(512, 6) void attn_fwd2(
    const __bf16* __restrict__ Qg, const __bf16* __restrict__ Kg,
    const __bf16* __restrict__ Vtg, __bf16* __restrict__ O) {
  __shared__ __bf16 Ks[2][64 * 64];
  __shared__ __bf16 Vs[2][64 * 64];
  __shared__ __bf16 Ps[128 * PSTR];
  const int tid = threadIdx.x, lane = tid & 63, wid = tid >> 6;
  const int bh = blockIdx.x, b = bh >> 4, h = bh & 15;
  const int qx = 15 - blockIdx.y;           // heavy blocks first
  const int qBase = qx * 128;
  const int qw = qBase + wid * 16;
  const int qwTop = qw + 15;
  const long bT = (long)b * T_;
  const int l15 = lane & 15, qtr = lane >> 4;
  const int q_lane = qw + l15;

  const int srow = tid >> 3;
  const int schunk = (tid & 7) ^ (srow & 7);
  const __bf16* kSrcBase = Kg + (bT + srow) * C_ + h * 64 + schunk * 8;
  const __bf16* vSrcBase = Vtg + (long)(h * 64 + srow) * BT_ + bT + schunk * 8;
  __bf16* kDst = &Ks[0][tid * 8];
  __bf16* vDst = &Vs[0][tid * 8];
  const int bufStride = 64 * 64;

  bf16x8 q0s, q1s;
  {
    const float SC = 0.125f * 1.44269504089f;  // 1/sqrt(64) * log2(e)
    bf16x8 r0 = *(const bf16x8*)(Qg + (bT + q_lane) * C_ + h * 64 + qtr * 8);
    bf16x8 r1 = *(const bf16x8*)(Qg + (bT + q_lane) * C_ + h * 64 + 32 + qtr * 8);
#pragma unroll
    for (int j = 0; j < 8; j++) {
      q0s[j] = (__bf16)((float)r0[j] * SC);
      q1s[j] = (__bf16)((float)r1[j] * SC);
    }
  }

  f32x4 o[4] = {};
  float m_ = -1e30f, l_ = 0.0f;
  const int nkt = 2 * qx + 2;

  gload_lds16(kSrcBase, kDst);
  gload_lds16(vSrcBase, vDst);
  __syncthreads();

  int buf = 0;
  for (int t = 0; t < nkt; t++) {
    const int k0 = t * 64;
    if (t + 1 < nkt) {
      const long koff = (long)(k0 + 64);
      gload_lds16(kSrcBase + koff * C_, kDst + (buf ^ 1) * bufStride);
      gload_lds16(vSrcBase + koff, vDst + (buf ^ 1) * bufStride);
    }
    if (k0 <= qwTop) {
      const __bf16* ks = Ks[buf];
      const __bf16* vs = Vs[buf];
      f32x4 sT[4] = {};
      __builtin_amdgcn_s_setprio(1);
#pragma unroll
      for (int kb = 0; kb < 4; kb++) {
        bf16x8 aK0 = *(const bf16x8*)&ks[(kb * 16 + l15) * 64 + ((qtr ^ (l15 & 7)) * 8)];
        bf16x8 aK1 = *(const bf16x8*)&ks[(kb * 16 + l15) * 64 + (((4 + qtr) ^ (l15 & 7)) * 8)];
        sT[kb] = __builtin_amdgcn_mfma_f32_16x16x32_bf16(aK0, q0s, sT[kb], 0, 0, 0);
        sT[kb] = __builtin_amdgcn_mfma_f32_16x16x32_bf16(aK1, q1s, sT[kb], 0, 0, 0);
      }
      __builtin_amdgcn_s_setprio(0);
      if (k0 + 63 > qw) {
#pragma unroll
        for (int kb = 0; kb < 4; kb++)
#pragma unroll
          for (int r = 0; r < 4; r++)
            if (k0 + kb * 16 + qtr * 4 + r > q_lane) sT[kb][r] = -1e30f;
      }
      float mx = -1e30f;
#pragma unroll
      for (int kb = 0; kb < 4; kb++)
#pragma unroll
        for (int r = 0; r < 4; r++) mx = fmaxf(mx, sT[kb][r]);
      mx = fmaxf(mx, __shfl_xor(mx, 16));
      mx = fmaxf(mx, __shfl_xor(mx, 32));
      // defer-max: skip rescale when no row grew by > 8 (log2 units; P <= 256)
      const bool defer = __all(mx - m_ <= 8.0f);
      const float mnew = defer ? m_ : fmaxf(m_, mx);
      float psum = 0.0f;
#pragma unroll
      for (int kb = 0; kb < 4; kb++)
#pragma unroll
        for (int r = 0; r < 4; r++) {
          const float pv = exp2f(sT[kb][r] - mnew);
          psum += pv;
          Ps[(wid * 16 + l15) * PSTR + kb * 16 + qtr * 4 + r] = (__bf16)pv;
        }
      psum += __shfl_xor(psum, 16);
      psum += __shfl_xor(psum, 32);
      if (defer) {
        l_ += psum;
      } else {
        const float fac = exp2f(m_ - mnew);
        l_ = l_ * fac + psum;
        m_ = mnew;
#pragma unroll
        for (int r = 0; r < 4; r++) {
          const float fr = __shfl(fac, (lane & 48) + qtr * 4 + r);
#pragma unroll
          for (int dg = 0; dg < 4; dg++) o[dg][r] *= fr;
        }
      }
      __builtin_amdgcn_s_setprio(1);
#pragma unroll
      for (int s = 0; s < 2; s++) {
        bf16x8 aP = *(const bf16x8*)&Ps[(wid * 16 + l15) * PSTR + s * 32 + qtr * 8];
#pragma unroll
        for (int dg = 0; dg < 4; dg++) {
          bf16x8 bV = *(const bf16x8*)&vs[(dg * 16 + l15) * 64 + (((s * 4 + qtr) ^ (l15 & 7)) * 8)];
          o[dg] = __builtin_amdgcn_mfma_f32_16x16x32_bf16(aP, bV, o[dg], 0, 0, 0);
        }
      }
      __builtin_amdgcn_s_setprio(0);
    }
    __syncthreads();
    buf ^= 1;
  }

  const float linv = 1.0f / l_;
#pragma unroll
  for (int r = 0; r < 4; r++) {
    const float lr = __shfl(linv, (lane & 48) + qtr * 4 + r);
    const long row = bT + qw + qtr * 4 + r;
#pragma unroll
    for (int dg = 0; dg < 4; dg++)
      O[row * C_ + h * 64 + dg * 16 + l15] = (__bf16)(o[dg][r] * lr);
  }
}

// ---------------- launch ----------------
extern "C" void kernel_launch(void* const* d_in, const int* in_sizes, int n_in,
                              void* d_out, int out_size, void* d_ws, size_t ws_size,
                              hipStream_t stream) {
  const float* x = (const float*)d_in[0];
  const float* wq = (const float*)d_in[1];
  const float* wk = (const float*)d_in[2];
  const float* wv = (const float*)d_in[3];
  const float* wproj = (const float*)d_in[4];
  const float* bproj = (const float*)d_in[5];
  const float* w1 = (const float*)d_in[6];
  const float* b1 = (const float*)d_in[7];
  const float* w2 = (const float*)d_in[8];
  const float* b2 = (const float*)d_in[9];
  const float* g1 = (const float*)d_in[10];
  const float* be1 = (const float*)d_in[11];
  const float* g2 = (const float*)d_in[12];
  const float* be2 = (const float*)d_in[13];

  char* ws = (char*)d_ws;
  const size_t MB = 1024ull * 1024ull;
  __bf16* h1 = (__bf16*)(ws + 0);          // 16MB; reused as att after QKV
  __bf16* Qb = (__bf16*)(ws + 16 * MB);    // 16MB; reused as h2 after attn
  __bf16* Kb = (__bf16*)(ws + 32 * MB);    // 16MB
  __bf16* Vtg = (__bf16*)(ws + 48 * MB);   // 16MB, V pre-transposed [C][B*T]
  __bf16* ff1 = (__bf16*)(ws + 32 * MB);   // 64MB, aliases Kb/Vtg (dead after attn)
  __bf16* wqt = (__bf16*)(ws + 96 * MB);   // wqt/wkt/wvt contiguous => [3072][1024]
  __bf16* wkt = (__bf16*)(ws + 98 * MB);
  __bf16* wvt = (__bf16*)(ws + 100 * MB);
  __bf16* wpt = (__bf16*)(ws + 102 * MB);
  __bf16* w1t = (__bf16*)(ws + 104 * MB);  // 8MB
  __bf16* w2t = (__bf16*)(ws + 112 * MB);  // 8MB
  __bf16* att = h1;
  __bf16* h2 = Qb;
  float* xout = (float*)d_out;

  dim3 tb(32, 8);
  transpose_f32_bf16<<<dim3(2, 32, 16), tb, 0, stream>>>(wq, wqt, 1024, 64, 1024 * 64, 64 * 1024);
  transpose_f32_bf16<<<dim3(2, 32, 16), tb, 0, stream>>>(wk, wkt, 1024, 64, 1024 * 64, 64 * 1024);
  transpose_f32_bf16<<<dim3(2, 32, 16), tb, 0, stream>>>(wv, wvt, 1024, 64, 1024 * 64, 64 * 1024);
  transpose_f32_bf16<<<dim3(32, 32, 1), tb, 0, stream>>>(wproj, wpt, 1024, 1024, 0, 0);
  transpose_f32_bf16<<<dim3(128, 32, 1), tb, 0, stream>>>(w1, w1t, 1024, 4096, 0, 0);
  transpose_f32_bf16<<<dim3(32, 128, 1), tb, 0, stream>>>(w2, w2t, 4096, 1024, 0, 0);

  ln_fwd<<<8192, 256, 0, stream>>>(x, g1, be1, h1);
  // fused QKV: Bt = [wqt|wkt|wvt] = [3072][1024]; 64 m-blocks x 12 n-blocks
  gemm8p<1><<<768, 512, 0, stream>>>(h1, wqt, Qb, Kb, Vtg, nullptr, nullptr, 8192, 3072, 1024, 768);
  attn_fwd2<<<dim3(64, 16), 512, 0, stream>>>(Qb, Kb, Vtg, att);
  gemm8p<2><<<256, 512, 0, stream>>>(att, wpt, xout, nullptr, nullptr, bproj, x, 8192, 1024, 1024, 256);
  ln_fwd<<<8192, 256, 0, stream>>>(xout, g2, be2, h2);
  gemm8p<0><<<1024, 512, 0, stream>>>(h2, w1t, ff1, nullptr, nullptr, b1, nullptr, 8192, 4096, 1024, 1024);
  gemm8p<2><<<256, 512, 0, stream>>>(ff1, w2t, xout, nullptr, nullptr, b2, (const float*)xout, 8192, 1024, 4096, 256);
}